// Round 1
// baseline (944.601 us; speedup 1.0000x reference)
//
#include <hip/hip_runtime.h>
#include <cstdint>
#include <cstddef>

// ---- problem constants (match reference) ----
#define Bn   4
#define Nn   4000
#define Gn   64
#define Cn   91
#define FGC  90          // C-1 foreground classes
#define CAPC 8192        // candidate capacity per image (V ~ 7200 expected)
#define MSEL 2048        // PRE_NMS_TOPK
#define DETK 100

__device__ __constant__ float kW = 1333.0f;
__device__ __constant__ float kH = 800.0f;
#define XCLIP 4.135166556742356f   // log(1000/16)
#define OFFMUL 1334.0f             // max(W,H)+1

// output layout (floats)
#define OUT_DET  0
#define OUT_REG  (Bn*DETK*5)                         // 2000
#define OUT_LBL  (OUT_REG + Bn*(Nn+Gn)*4)            // 67024
#define OUT_DETL (OUT_LBL + Bn*(Nn+Gn))              // 83280

// ---------------- kernel 1: per-row softmax stats (max, sumexp) ----------------
__global__ __launch_bounds__(256) void rowstats_k(const float* __restrict__ logits,
                                                  float* __restrict__ rowstats) {
    int wave = threadIdx.x >> 6, lane = threadIdx.x & 63;
    int row = blockIdx.x * 4 + wave;               // [0, B*N)
    if (row >= Bn * Nn) return;
    const float* z = logits + (size_t)row * Cn;
    float v0 = z[lane];                            // lane < 91 always
    float v1 = (lane + 64 < Cn) ? z[lane + 64] : -INFINITY;
    float m = fmaxf(v0, v1);
    #pragma unroll
    for (int o = 32; o; o >>= 1) m = fmaxf(m, __shfl_xor(m, o));
    float e = expf(v0 - m) + ((lane + 64 < Cn) ? expf(v1 - m) : 0.0f);
    #pragma unroll
    for (int o = 32; o; o >>= 1) e += __shfl_xor(e, o);
    if (lane == 0) { rowstats[row * 2] = m; rowstats[row * 2 + 1] = e; }
}

// ---------------- decode helper (must be bit-identical between kernels) ----------------
__device__ __forceinline__ void decode_box(float4 p, float4 d,
                                           float& bx1, float& by1, float& bx2, float& by2) {
    float pw = p.z - p.x, ph = p.w - p.y;
    float px = p.x + 0.5f * pw, py = p.y + 0.5f * ph;
    float dx = d.x / 10.0f, dy = d.y / 10.0f;
    float dw = fminf(d.z / 5.0f, XCLIP), dh = fminf(d.w / 5.0f, XCLIP);
    float cx = dx * pw + px, cy = dy * ph + py;
    float w = expf(dw) * pw, h = expf(dh) * ph;
    bx1 = fminf(fmaxf(cx - 0.5f * w, 0.0f), kW);
    by1 = fminf(fmaxf(cy - 0.5f * h, 0.0f), kH);
    bx2 = fminf(fmaxf(cx + 0.5f * w, 0.0f), kW);
    by2 = fminf(fmaxf(cy + 0.5f * h, 0.0f), kH);
}

// ---------------- kernel 2: compact valid candidates to key list ----------------
__global__ __launch_bounds__(256) void cand_k(const float* __restrict__ logits,
                                              const float* __restrict__ regr,
                                              const float* __restrict__ props,
                                              const float* __restrict__ rowstats,
                                              unsigned long long* __restrict__ keys,
                                              unsigned int* __restrict__ cnt) {
    int t = blockIdx.x * 256 + threadIdx.x;        // over B*N*90, class fastest
    if (t >= Bn * Nn * FGC) return;
    int b = t / (Nn * FGC);
    int r = t - b * (Nn * FGC);
    int n = r / FGC, cm1 = r - n * FGC, c = cm1 + 1;
    int row = b * Nn + n;
    float z = logits[(size_t)row * Cn + c];
    float score = expf(z - rowstats[row * 2]) / rowstats[row * 2 + 1];
    if (!(score > 0.05f)) return;
    float4 p = ((const float4*)props)[row];
    float4 d = ((const float4*)regr)[(size_t)row * Cn + c];
    float bx1, by1, bx2, by2;
    decode_box(p, d, bx1, by1, bx2, by2);
    if (!((bx2 - bx1 >= 0.01f) && (by2 - by1 >= 0.01f))) return;
    unsigned idx = (unsigned)(n * FGC + cm1);
    unsigned long long key = ((unsigned long long)__float_as_uint(score) << 32) |
                             (unsigned long long)(~idx);
    unsigned pos = atomicAdd(&cnt[b], 1u);
    if (pos < CAPC) keys[(size_t)b * CAPC + pos] = key;
}

// ---------------- kernel 3: per-image bitonic sort (descending), take top 2048 ----------------
__global__ __launch_bounds__(1024) void sort_k(const unsigned long long* __restrict__ keys,
                                               const unsigned int* __restrict__ cnt,
                                               unsigned long long* __restrict__ selkeys) {
    __shared__ unsigned long long sk[CAPC];        // 64 KiB
    int b = blockIdx.x;
    unsigned V = cnt[b]; if (V > CAPC) V = CAPC;
    for (int s = threadIdx.x; s < CAPC; s += 1024)
        sk[s] = (s < (int)V) ? keys[(size_t)b * CAPC + s] : 0ull;
    __syncthreads();
    for (int k = 2; k <= CAPC; k <<= 1) {
        for (int j = k >> 1; j > 0; j >>= 1) {
            for (int s = threadIdx.x; s < CAPC; s += 1024) {
                int l = s ^ j;
                if (l > s) {
                    unsigned long long a = sk[s], c2 = sk[l];
                    bool descSeg = ((s & k) == 0);
                    bool sw = descSeg ? (a < c2) : (a > c2);
                    if (sw) { sk[s] = c2; sk[l] = a; }
                }
            }
            __syncthreads();
        }
    }
    for (int s = threadIdx.x; s < MSEL; s += 1024)
        selkeys[b * MSEL + s] = sk[s];
}

// ---------------- kernel 4: materialize selected candidates ----------------
__global__ __launch_bounds__(256) void select_k(const unsigned long long* __restrict__ selkeys,
                                                const float* __restrict__ props,
                                                const float* __restrict__ regr,
                                                float* __restrict__ cb, float* __restrict__ ob,
                                                float* __restrict__ sc, int* __restrict__ lab,
                                                unsigned int* __restrict__ cv) {
    int t = blockIdx.x * 256 + threadIdx.x;        // B*2048
    if (t >= Bn * MSEL) return;
    int b = t >> 11;
    unsigned long long key = selkeys[t];
    float bx1 = 0, by1 = 0, bx2 = 0, by2 = 0, score = 0;
    int c = 0; unsigned valid = 0;
    if ((key >> 32) != 0ull) {
        valid = 1;
        unsigned idx = ~(unsigned)key;
        int n = idx / FGC, cm1 = idx - n * FGC;
        c = cm1 + 1;
        score = __uint_as_float((unsigned)(key >> 32));
        int row = b * Nn + n;
        float4 p = ((const float4*)props)[row];
        float4 d = ((const float4*)regr)[(size_t)row * Cn + c];
        decode_box(p, d, bx1, by1, bx2, by2);
    }
    float off = (float)c * OFFMUL;
    cb[t * 4 + 0] = bx1; cb[t * 4 + 1] = by1; cb[t * 4 + 2] = bx2; cb[t * 4 + 3] = by2;
    ob[t * 4 + 0] = bx1 + off; ob[t * 4 + 1] = by1 + off;
    ob[t * 4 + 2] = bx2 + off; ob[t * 4 + 3] = by2 + off;
    sc[t] = score; lab[t] = c; cv[t] = valid;
}

// ---------------- kernel 5: suppression bitmask matrix M[b][i][w] ----------------
__global__ __launch_bounds__(256) void nmsmat_k(const float* __restrict__ ob,
                                                unsigned long long* __restrict__ M) {
    __shared__ float4 sb[MSEL];                    // 32 KiB
    int b = blockIdx.x >> 5, chunk = blockIdx.x & 31;   // 32 chunks of 64 rows
    const float4* obf4 = (const float4*)(ob + (size_t)b * MSEL * 4);
    for (int s = threadIdx.x; s < MSEL; s += 256) sb[s] = obf4[s];
    __syncthreads();
    int w = threadIdx.x & 31, i0 = threadIdx.x >> 5;    // i0 in 0..7
    #pragma unroll 1
    for (int r = 0; r < 8; ++r) {
        int i = chunk * 64 + r * 8 + i0;
        float4 bi = sb[i];
        float areai = (bi.z - bi.x) * (bi.w - bi.y);
        unsigned long long bits = 0ull;
        for (int tt = 0; tt < 64; ++tt) {
            int j = w * 64 + tt;
            float4 bj = sb[j];
            float xx1 = fmaxf(bi.x, bj.x), yy1 = fmaxf(bi.y, bj.y);
            float xx2 = fminf(bi.z, bj.z), yy2 = fminf(bi.w, bj.w);
            float iw = fmaxf(xx2 - xx1, 0.0f), ih = fmaxf(yy2 - yy1, 0.0f);
            float inter = iw * ih;
            float areaj = (bj.z - bj.x) * (bj.w - bj.y);
            float iou = inter / (areai + areaj - inter);   // NaN>0.5 is false: matches JAX
            if ((iou > 0.5f) && (j > i)) bits |= (1ull << tt);
        }
        M[((size_t)b * MSEL + i) * 32 + w] = bits;
    }
}

// ---------------- kernel 6: sequential greedy scan (one wave per image) + det output ----------------
__global__ __launch_bounds__(64) void scan_k(const unsigned long long* __restrict__ M,
                                             const unsigned int* __restrict__ cv,
                                             const float* __restrict__ cb,
                                             const float* __restrict__ sc,
                                             const int* __restrict__ lab,
                                             float* __restrict__ out) {
    int b = blockIdx.x, lane = threadIdx.x;
    // build keep init from cv: lane w owns keep word w (bit t = candidate w*64+t)
    unsigned long long keep = 0ull;
    for (int w = 0; w < 32; ++w) {
        unsigned long long bw = __ballot(cv[b * MSEL + w * 64 + lane] != 0u);
        if (lane == w) keep = bw;
    }
    const unsigned long long* Mb = M + (size_t)b * MSEL * 32;
    const bool ld = lane < 32;
    unsigned long long Abuf[16], Bbuf[16];
    #pragma unroll
    for (int k = 0; k < 16; ++k) Abuf[k] = ld ? Mb[(size_t)k * 32 + lane] : 0ull;
    for (int g = 0; g < 128; g += 2) {
        #pragma unroll
        for (int k = 0; k < 16; ++k)
            Bbuf[k] = ld ? Mb[(size_t)((g + 1) * 16 + k) * 32 + lane] : 0ull;
        #pragma unroll
        for (int k = 0; k < 16; ++k) {
            int i = g * 16 + k;
            unsigned long long kw = __shfl(keep, i >> 6);
            if ((kw >> (i & 63)) & 1ull) keep &= ~Abuf[k];
        }
        if (g + 2 < 128) {
            #pragma unroll
            for (int k = 0; k < 16; ++k)
                Abuf[k] = ld ? Mb[(size_t)((g + 2) * 16 + k) * 32 + lane] : 0ull;
        }
        #pragma unroll
        for (int k = 0; k < 16; ++k) {
            int i = (g + 1) * 16 + k;
            unsigned long long kw = __shfl(keep, i >> 6);
            if ((kw >> (i & 63)) & 1ull) keep &= ~Bbuf[k];
        }
    }
    // rank + scatter first 100 kept
    int cnt_w = __popcll(keep);                     // lanes >=32 hold 0
    int inc = cnt_w;
    #pragma unroll
    for (int o = 1; o < 32; o <<= 1) { int v = __shfl_up(inc, o); if (lane >= o) inc += v; }
    int pre = inc - cnt_w;
    int total = __shfl(inc, 31);
    if (lane < 32) {
        unsigned long long wbits = keep;
        int r = pre;
        while (wbits) {
            int tt = __ffsll((unsigned long long)wbits) - 1;
            wbits &= wbits - 1;
            if (r < DETK) {
                int slot = b * MSEL + lane * 64 + tt;
                float* dr = out + OUT_DET + ((size_t)b * DETK + r) * 5;
                dr[0] = cb[slot * 4 + 0]; dr[1] = cb[slot * 4 + 1];
                dr[2] = cb[slot * 4 + 2]; dr[3] = cb[slot * 4 + 3];
                dr[4] = sc[slot];
                out[OUT_DETL + b * DETK + r] = (float)lab[slot];
            }
            ++r;
        }
    }
    int total100 = total < DETK ? total : DETK;
    for (int r = total100 + lane; r < DETK; r += 64) {
        float* dr = out + OUT_DET + ((size_t)b * DETK + r) * 5;
        dr[0] = dr[1] = dr[2] = dr[3] = dr[4] = 0.0f;
        out[OUT_DETL + b * DETK + r] = 0.0f;
    }
}

// ---------------- kernel 7: proposal->gt matching, reg_targets + lbl ----------------
__global__ __launch_bounds__(256) void assign_k(const float* __restrict__ props,
                                                const float* __restrict__ gtb,
                                                const int* __restrict__ gtl,
                                                float* __restrict__ out) {
    __shared__ float4 sg[Gn];
    int b = blockIdx.y;
    int p = blockIdx.x * 256 + threadIdx.x;
    if (threadIdx.x < Gn) sg[threadIdx.x] = ((const float4*)(gtb + (size_t)b * Gn * 4))[threadIdx.x];
    __syncthreads();
    if (p >= Nn + Gn) return;
    float4 pb = (p < Nn) ? ((const float4*)(props + (size_t)b * Nn * 4))[p] : sg[p - Nn];
    float areap = (pb.z - pb.x) * (pb.w - pb.y);
    float best = -1.0f; int bi = 0;
    #pragma unroll 4
    for (int g = 0; g < Gn; ++g) {
        float4 gb = sg[g];
        float xx1 = fmaxf(gb.x, pb.x), yy1 = fmaxf(gb.y, pb.y);
        float xx2 = fminf(gb.z, pb.z), yy2 = fminf(gb.w, pb.w);
        float iw = fmaxf(xx2 - xx1, 0.0f), ih = fmaxf(yy2 - yy1, 0.0f);
        float inter = iw * ih;
        float areag = (gb.z - gb.x) * (gb.w - gb.y);
        float iou = inter / (areag + areap - inter);
        if (iou > best) { best = iou; bi = g; }     // strict > : first-max, matches argmax
    }
    float4 gb = sg[bi];
    float pw = pb.z - pb.x, ph = pb.w - pb.y;
    float px = pb.x + 0.5f * pw, py = pb.y + 0.5f * ph;
    float gw = gb.z - gb.x, gh = gb.w - gb.y;
    float gx = gb.x + 0.5f * gw, gy = gb.y + 0.5f * gh;
    float* rr = out + OUT_REG + ((size_t)b * (Nn + Gn) + p) * 4;
    rr[0] = 10.0f * (gx - px) / pw;
    rr[1] = 10.0f * (gy - py) / ph;
    rr[2] = 5.0f * logf(gw / pw);
    rr[3] = 5.0f * logf(gh / ph);
    out[OUT_LBL + (size_t)b * (Nn + Gn) + p] = (best >= 0.5f) ? (float)gtl[b * Gn + bi] : 0.0f;
}

// ---------------- launch ----------------
extern "C" void kernel_launch(void* const* d_in, const int* in_sizes, int n_in,
                              void* d_out, int out_size, void* d_ws, size_t ws_size,
                              hipStream_t stream) {
    const float* props  = (const float*)d_in[0];
    const float* gtb    = (const float*)d_in[1];
    const int*   gtl    = (const int*)d_in[2];
    const float* logits = (const float*)d_in[3];
    const float* regr   = (const float*)d_in[4];
    float* out = (float*)d_out;

    // ws layout (256B aligned sections)
    char* w = (char*)d_ws;
    unsigned int* cnt           = (unsigned int*)(w + 0);                    // 16 B
    float* rowstats             = (float*)(w + 256);                         // 128000 B
    unsigned long long* keys    = (unsigned long long*)(w + 128256);         // 262144 B
    unsigned long long* selkeys = (unsigned long long*)(w + 390400);         // 65536 B
    float* cb                   = (float*)(w + 455936);                      // 131072 B
    float* ob                   = (float*)(w + 587008);                      // 131072 B
    float* sc                   = (float*)(w + 718080);                      // 32768 B
    int* lab                    = (int*)(w + 750848);                        // 32768 B
    unsigned int* cv            = (unsigned int*)(w + 783616);               // 32768 B
    unsigned long long* M       = (unsigned long long*)(w + 816384);         // 2097152 B
    (void)ws_size; (void)in_sizes; (void)n_in; (void)out_size;

    hipMemsetAsync(cnt, 0, Bn * sizeof(unsigned int), stream);

    rowstats_k<<<(Bn * Nn) / 4, 256, 0, stream>>>(logits, rowstats);
    cand_k<<<(Bn * Nn * FGC + 255) / 256, 256, 0, stream>>>(logits, regr, props, rowstats, keys, cnt);
    sort_k<<<Bn, 1024, 0, stream>>>(keys, cnt, selkeys);
    select_k<<<(Bn * MSEL) / 256, 256, 0, stream>>>(selkeys, props, regr, cb, ob, sc, lab, cv);
    nmsmat_k<<<Bn * 32, 256, 0, stream>>>(ob, M);
    scan_k<<<Bn, 64, 0, stream>>>(M, cv, cb, sc, lab, out);
    assign_k<<<dim3((Nn + Gn + 255) / 256, Bn), 256, 0, stream>>>(props, gtb, gtl, out);
}

// Round 2
// 486.638 us; speedup vs baseline: 1.9411x; 1.9411x over previous
//
#include <hip/hip_runtime.h>
#include <cstdint>
#include <cstddef>

// ---- problem constants (match reference) ----
#define Bn   4
#define Nn   4000
#define Gn   64
#define Cn   91
#define FGC  90          // C-1 foreground classes
#define CAPC 16384       // candidate capacity per image (V ~ 7-8K expected)
#define MSEL 2048        // PRE_NMS_TOPK
#define DETK 100

__device__ __constant__ float kW = 1333.0f;
__device__ __constant__ float kH = 800.0f;
#define XCLIP 4.135166556742356f   // log(1000/16)
#define OFFMUL 1334.0f             // max(W,H)+1

// output layout (floats)
#define OUT_DET  0
#define OUT_REG  (Bn*DETK*5)                         // 2000
#define OUT_LBL  (OUT_REG + Bn*(Nn+Gn)*4)            // 67024
#define OUT_DETL (OUT_LBL + Bn*(Nn+Gn))              // 83280

// ---------------- kernel 1: per-row softmax stats (max, sumexp) ----------------
__global__ __launch_bounds__(256) void rowstats_k(const float* __restrict__ logits,
                                                  float* __restrict__ rowstats) {
    int wave = threadIdx.x >> 6, lane = threadIdx.x & 63;
    int row = blockIdx.x * 4 + wave;               // [0, B*N)
    if (row >= Bn * Nn) return;
    const float* z = logits + (size_t)row * Cn;
    float v0 = z[lane];                            // lane < 91 always
    float v1 = (lane + 64 < Cn) ? z[lane + 64] : -INFINITY;
    float m = fmaxf(v0, v1);
    #pragma unroll
    for (int o = 32; o; o >>= 1) m = fmaxf(m, __shfl_xor(m, o));
    float e = expf(v0 - m) + ((lane + 64 < Cn) ? expf(v1 - m) : 0.0f);
    #pragma unroll
    for (int o = 32; o; o >>= 1) e += __shfl_xor(e, o);
    if (lane == 0) { rowstats[row * 2] = m; rowstats[row * 2 + 1] = e; }
}

// ---------------- decode helper (must be bit-identical between kernels) ----------------
__device__ __forceinline__ void decode_box(float4 p, float4 d,
                                           float& bx1, float& by1, float& bx2, float& by2) {
    float pw = p.z - p.x, ph = p.w - p.y;
    float px = p.x + 0.5f * pw, py = p.y + 0.5f * ph;
    float dx = d.x / 10.0f, dy = d.y / 10.0f;
    float dw = fminf(d.z / 5.0f, XCLIP), dh = fminf(d.w / 5.0f, XCLIP);
    float cx = dx * pw + px, cy = dy * ph + py;
    float w = expf(dw) * pw, h = expf(dh) * ph;
    bx1 = fminf(fmaxf(cx - 0.5f * w, 0.0f), kW);
    by1 = fminf(fmaxf(cy - 0.5f * h, 0.0f), kH);
    bx2 = fminf(fmaxf(cx + 0.5f * w, 0.0f), kW);
    by2 = fminf(fmaxf(cy + 0.5f * h, 0.0f), kH);
}

// ---------------- kernel 2: compact valid candidates to key list ----------------
__global__ __launch_bounds__(256) void cand_k(const float* __restrict__ logits,
                                              const float* __restrict__ regr,
                                              const float* __restrict__ props,
                                              const float* __restrict__ rowstats,
                                              unsigned long long* __restrict__ keys,
                                              unsigned int* __restrict__ cnt) {
    int t = blockIdx.x * 256 + threadIdx.x;        // over B*N*90, class fastest
    if (t >= Bn * Nn * FGC) return;
    int b = t / (Nn * FGC);
    int r = t - b * (Nn * FGC);
    int n = r / FGC, cm1 = r - n * FGC, c = cm1 + 1;
    int row = b * Nn + n;
    float z = logits[(size_t)row * Cn + c];
    float score = expf(z - rowstats[row * 2]) / rowstats[row * 2 + 1];
    if (!(score > 0.05f)) return;
    float4 p = ((const float4*)props)[row];
    float4 d = ((const float4*)regr)[(size_t)row * Cn + c];
    float bx1, by1, bx2, by2;
    decode_box(p, d, bx1, by1, bx2, by2);
    if (!((bx2 - bx1 >= 0.01f) && (by2 - by1 >= 0.01f))) return;
    unsigned idx = (unsigned)(n * FGC + cm1);
    unsigned long long key = ((unsigned long long)__float_as_uint(score) << 32) |
                             (unsigned long long)(~idx);
    unsigned pos = atomicAdd(&cnt[b], 1u);
    if (pos < CAPC) keys[(size_t)b * CAPC + pos] = key;
}

// ---------------- kernel 3: histogram-select top-2048 superset, sort it ----------------
// Score bits are positive floats in (0.05, 1] -> uint-monotonic. Bucket by
// (bits - 0x3D400000) >> 12 (9216 buckets). Select all buckets above the one
// containing the 2048th-largest key, plus that whole bucket (superset, n2 ~ 2050),
// scatter into 4096-slot LDS (zero pad), pair-indexed bitonic sort descending,
// emit first 2048. Fallback to full 8192 sort if a pathological tie cluster
// makes n2 > 4096 (cannot occur with these inputs; correctness path only).
#define NB 9216
#define SBIAS 0x3D400000u

__global__ __launch_bounds__(1024) void sort_k(const unsigned long long* __restrict__ keys,
                                               const unsigned int* __restrict__ cnt,
                                               unsigned long long* __restrict__ selkeys) {
    __shared__ unsigned hist[NB];                  // 36 KiB
    __shared__ unsigned soff[NB];                  // 36 KiB (becomes scatter cursor)
    __shared__ unsigned cs[1024];                  // 4 KiB
    __shared__ unsigned long long sk[8192];        // 64 KiB
    __shared__ int sT; __shared__ unsigned sn2;
    int b = blockIdx.x, tid = threadIdx.x;
    unsigned V = cnt[b]; if (V > CAPC) V = CAPC;
    unsigned K2 = V < MSEL ? V : MSEL;

    for (int h = tid; h < NB; h += 1024) hist[h] = 0;
    if (tid == 0) { sT = NB; sn2 = 0; }
    __syncthreads();
    if (K2 == 0) {                                 // no candidates: emit zeros
        for (int s = tid; s < MSEL; s += 1024) selkeys[b * MSEL + s] = 0ull;
        return;
    }
    for (unsigned s = tid; s < V; s += 1024) {
        unsigned sb = (unsigned)(keys[(size_t)b * CAPC + s] >> 32);
        unsigned h = (sb - SBIAS) >> 12; if (h > NB - 1) h = NB - 1;
        atomicAdd(&hist[h], 1u);
    }
    __syncthreads();
    // per-thread chunk sums (9 buckets each), suffix-scan chunks, then per-bucket
    unsigned csum = 0;
    #pragma unroll
    for (int q = 0; q < 9; ++q) csum += hist[tid * 9 + q];
    cs[tid] = csum; __syncthreads();
    for (int off = 1; off < 1024; off <<= 1) {
        unsigned v = (tid + off < 1024) ? cs[tid + off] : 0u; __syncthreads();
        cs[tid] += v; __syncthreads();
    }
    unsigned run = cs[tid] - csum;                 // keys in buckets of higher chunks
    #pragma unroll
    for (int q = 8; q >= 0; --q) { soff[tid * 9 + q] = run; run += hist[tid * 9 + q]; }
    __syncthreads();
    // find pivot bucket T: soff[T] < K2 <= soff[T]+hist[T]
    #pragma unroll
    for (int q = 0; q < 9; ++q) {
        int h = tid * 9 + q;
        unsigned lo = soff[h], hi = lo + hist[h];
        if (lo < K2 && K2 <= hi) { sT = h; sn2 = hi; }
    }
    __syncthreads();
    int T = sT; unsigned n2 = sn2;
    unsigned P = (n2 <= 4096u) ? 4096u : 8192u;
    for (unsigned s = tid; s < P; s += 1024) sk[s] = 0ull;
    __syncthreads();
    if (n2 <= 4096u) {
        for (unsigned s = tid; s < V; s += 1024) {
            unsigned long long key = keys[(size_t)b * CAPC + s];
            unsigned sb = (unsigned)(key >> 32);
            unsigned h = (sb - SBIAS) >> 12; if (h > NB - 1) h = NB - 1;
            if ((int)h >= T) { unsigned pos = atomicAdd(&soff[h], 1u); sk[pos] = key; }
        }
    } else {                                       // pathological fallback: sort first 8192
        unsigned VL = V < 8192u ? V : 8192u;
        for (unsigned s = tid; s < VL; s += 1024) sk[s] = keys[(size_t)b * CAPC + s];
    }
    __syncthreads();
    // pair-indexed bitonic sort, descending, P elements
    for (unsigned k = 2; k <= P; k <<= 1) {
        for (unsigned j = k >> 1; j > 0; j >>= 1) {
            for (unsigned p = tid; p < (P >> 1); p += 1024) {
                unsigned s = ((p & ~(j - 1)) << 1) | (p & (j - 1));
                unsigned l = s | j;
                unsigned long long a = sk[s], c2 = sk[l];
                bool descSeg = ((s & k) == 0);
                bool sw = descSeg ? (a < c2) : (a > c2);
                if (sw) { sk[s] = c2; sk[l] = a; }
            }
            __syncthreads();
        }
    }
    for (int s = tid; s < MSEL; s += 1024) selkeys[b * MSEL + s] = sk[s];
}

// ---------------- kernel 4: materialize selected candidates ----------------
__global__ __launch_bounds__(256) void select_k(const unsigned long long* __restrict__ selkeys,
                                                const float* __restrict__ props,
                                                const float* __restrict__ regr,
                                                float* __restrict__ cb, float* __restrict__ ob,
                                                float* __restrict__ sc, int* __restrict__ lab,
                                                unsigned long long* __restrict__ cvw) {
    int t = blockIdx.x * 256 + threadIdx.x;        // B*2048
    if (t >= Bn * MSEL) return;
    int b = t >> 11;
    unsigned long long key = selkeys[t];
    float bx1 = 0, by1 = 0, bx2 = 0, by2 = 0, score = 0;
    int c = 0; unsigned valid = 0;
    if ((key >> 32) != 0ull) {
        valid = 1;
        unsigned idx = ~(unsigned)key;
        int n = idx / FGC, cm1 = idx - n * FGC;
        c = cm1 + 1;
        score = __uint_as_float((unsigned)(key >> 32));
        int row = b * Nn + n;
        float4 p = ((const float4*)props)[row];
        float4 d = ((const float4*)regr)[(size_t)row * Cn + c];
        decode_box(p, d, bx1, by1, bx2, by2);
    }
    float off = (float)c * OFFMUL;
    cb[t * 4 + 0] = bx1; cb[t * 4 + 1] = by1; cb[t * 4 + 2] = bx2; cb[t * 4 + 3] = by2;
    ob[t * 4 + 0] = bx1 + off; ob[t * 4 + 1] = by1 + off;
    ob[t * 4 + 2] = bx2 + off; ob[t * 4 + 3] = by2 + off;
    sc[t] = score; lab[t] = c;
    unsigned long long bw = __ballot(valid != 0u); // pack keep-init words here
    if ((t & 63) == 0) cvw[t >> 6] = bw;
}

// ---------------- kernel 5: suppression bitmask matrix M[b][i][w] ----------------
__global__ __launch_bounds__(256) void nmsmat_k(const float* __restrict__ ob,
                                                unsigned long long* __restrict__ M) {
    __shared__ float4 sb[MSEL];                    // 32 KiB
    int b = blockIdx.x >> 5, chunk = blockIdx.x & 31;   // 32 chunks of 64 rows
    const float4* obf4 = (const float4*)(ob + (size_t)b * MSEL * 4);
    for (int s = threadIdx.x; s < MSEL; s += 256) sb[s] = obf4[s];
    __syncthreads();
    int w = threadIdx.x & 31, i0 = threadIdx.x >> 5;    // i0 in 0..7
    #pragma unroll 1
    for (int r = 0; r < 8; ++r) {
        int i = chunk * 64 + r * 8 + i0;
        float4 bi = sb[i];
        float areai = (bi.z - bi.x) * (bi.w - bi.y);
        unsigned long long bits = 0ull;
        for (int tt = 0; tt < 64; ++tt) {
            int j = w * 64 + tt;
            float4 bj = sb[j];
            float xx1 = fmaxf(bi.x, bj.x), yy1 = fmaxf(bi.y, bj.y);
            float xx2 = fminf(bi.z, bj.z), yy2 = fminf(bi.w, bj.w);
            float iw = fmaxf(xx2 - xx1, 0.0f), ih = fmaxf(yy2 - yy1, 0.0f);
            float inter = iw * ih;
            float areaj = (bj.z - bj.x) * (bj.w - bj.y);
            float iou = inter / (areai + areaj - inter);   // NaN>0.5 is false: matches JAX
            if ((iou > 0.5f) && (j > i)) bits |= (1ull << tt);
        }
        M[((size_t)b * MSEL + i) * 32 + w] = bits;
    }
}

// ---------------- kernel 6: sequential greedy scan (one wave per image) + det output ----------------
// Bit broadcast via v_readlane (VALU, no LDS); early exit once 100 candidates
// are kept (output only uses the first DETK kept; keep determination is in
// scan order, so ranks < 100 are final at that point).
__global__ __launch_bounds__(64) void scan_k(const unsigned long long* __restrict__ M,
                                             const unsigned long long* __restrict__ cvw,
                                             const float* __restrict__ cb,
                                             const float* __restrict__ sc,
                                             const int* __restrict__ lab,
                                             float* __restrict__ out) {
    int b = blockIdx.x, lane = threadIdx.x;
    const bool ld = lane < 32;
    unsigned long long keep = ld ? cvw[b * 32 + lane] : 0ull;
    unsigned kLo = (unsigned)keep, kHi = (unsigned)(keep >> 32);
    __shared__ int keptIdx[DETK];
    const unsigned long long* Mb = M + (size_t)b * MSEL * 32;
    int kcount = 0;                                 // wave-uniform (tests come from readlane)
    unsigned long long Abuf[16], Bbuf[16];
    #pragma unroll
    for (int k = 0; k < 16; ++k) Abuf[k] = ld ? Mb[(size_t)k * 32 + lane] : 0ull;
    for (int g = 0; g < 128; g += 2) {
        #pragma unroll
        for (int k = 0; k < 16; ++k)
            Bbuf[k] = ld ? Mb[(size_t)((g + 1) * 16 + k) * 32 + lane] : 0ull;
        {
            int base = g * 16;
            int rl = base >> 6, sh = base & 31;     // uniform within group
            unsigned half = (base >> 5) & 1;
            #pragma unroll
            for (int k = 0; k < 16; ++k) {
                unsigned kw = half ? kHi : kLo;
                unsigned bitv = (__builtin_amdgcn_readlane(kw, rl) >> (sh + k)) & 1u;
                if (bitv) {
                    unsigned long long m = Abuf[k];
                    kLo &= ~(unsigned)m; kHi &= ~(unsigned)(m >> 32);
                    if (kcount < DETK && lane == 0) keptIdx[kcount] = base + k;
                    ++kcount;
                }
            }
        }
        if (kcount >= DETK) break;
        if (g + 2 < 128) {
            #pragma unroll
            for (int k = 0; k < 16; ++k)
                Abuf[k] = ld ? Mb[(size_t)((g + 2) * 16 + k) * 32 + lane] : 0ull;
        }
        {
            int base = (g + 1) * 16;
            int rl = base >> 6, sh = base & 31;
            unsigned half = (base >> 5) & 1;
            #pragma unroll
            for (int k = 0; k < 16; ++k) {
                unsigned kw = half ? kHi : kLo;
                unsigned bitv = (__builtin_amdgcn_readlane(kw, rl) >> (sh + k)) & 1u;
                if (bitv) {
                    unsigned long long m = Bbuf[k];
                    kLo &= ~(unsigned)m; kHi &= ~(unsigned)(m >> 32);
                    if (kcount < DETK && lane == 0) keptIdx[kcount] = base + k;
                    ++kcount;
                }
            }
        }
        if (kcount >= DETK) break;
    }
    __syncthreads();                                // lgkmcnt drain for keptIdx
    int kept100 = kcount < DETK ? kcount : DETK;
    for (int r = lane; r < kept100; r += 64) {
        int i = keptIdx[r];
        int slot = b * MSEL + i;
        float* dr = out + OUT_DET + ((size_t)b * DETK + r) * 5;
        dr[0] = cb[slot * 4 + 0]; dr[1] = cb[slot * 4 + 1];
        dr[2] = cb[slot * 4 + 2]; dr[3] = cb[slot * 4 + 3];
        dr[4] = sc[slot];
        out[OUT_DETL + b * DETK + r] = (float)lab[slot];
    }
    for (int r = kept100 + lane; r < DETK; r += 64) {
        float* dr = out + OUT_DET + ((size_t)b * DETK + r) * 5;
        dr[0] = dr[1] = dr[2] = dr[3] = dr[4] = 0.0f;
        out[OUT_DETL + b * DETK + r] = 0.0f;
    }
}

// ---------------- kernel 7: proposal->gt matching, reg_targets + lbl ----------------
__global__ __launch_bounds__(256) void assign_k(const float* __restrict__ props,
                                                const float* __restrict__ gtb,
                                                const int* __restrict__ gtl,
                                                float* __restrict__ out) {
    __shared__ float4 sg[Gn];
    int b = blockIdx.y;
    int p = blockIdx.x * 256 + threadIdx.x;
    if (threadIdx.x < Gn) sg[threadIdx.x] = ((const float4*)(gtb + (size_t)b * Gn * 4))[threadIdx.x];
    __syncthreads();
    if (p >= Nn + Gn) return;
    float4 pb = (p < Nn) ? ((const float4*)(props + (size_t)b * Nn * 4))[p] : sg[p - Nn];
    float areap = (pb.z - pb.x) * (pb.w - pb.y);
    float best = -1.0f; int bi = 0;
    #pragma unroll 4
    for (int g = 0; g < Gn; ++g) {
        float4 gb = sg[g];
        float xx1 = fmaxf(gb.x, pb.x), yy1 = fmaxf(gb.y, pb.y);
        float xx2 = fminf(gb.z, pb.z), yy2 = fminf(gb.w, pb.w);
        float iw = fmaxf(xx2 - xx1, 0.0f), ih = fmaxf(yy2 - yy1, 0.0f);
        float inter = iw * ih;
        float areag = (gb.z - gb.x) * (gb.w - gb.y);
        float iou = inter / (areag + areap - inter);
        if (iou > best) { best = iou; bi = g; }     // strict > : first-max, matches argmax
    }
    float4 gb = sg[bi];
    float pw = pb.z - pb.x, ph = pb.w - pb.y;
    float px = pb.x + 0.5f * pw, py = pb.y + 0.5f * ph;
    float gw = gb.z - gb.x, gh = gb.w - gb.y;
    float gx = gb.x + 0.5f * gw, gy = gb.y + 0.5f * gh;
    float* rr = out + OUT_REG + ((size_t)b * (Nn + Gn) + p) * 4;
    rr[0] = 10.0f * (gx - px) / pw;
    rr[1] = 10.0f * (gy - py) / ph;
    rr[2] = 5.0f * logf(gw / pw);
    rr[3] = 5.0f * logf(gh / ph);
    out[OUT_LBL + (size_t)b * (Nn + Gn) + p] = (best >= 0.5f) ? (float)gtl[b * Gn + bi] : 0.0f;
}

// ---------------- launch ----------------
extern "C" void kernel_launch(void* const* d_in, const int* in_sizes, int n_in,
                              void* d_out, int out_size, void* d_ws, size_t ws_size,
                              hipStream_t stream) {
    const float* props  = (const float*)d_in[0];
    const float* gtb    = (const float*)d_in[1];
    const int*   gtl    = (const int*)d_in[2];
    const float* logits = (const float*)d_in[3];
    const float* regr   = (const float*)d_in[4];
    float* out = (float*)d_out;

    // ws layout
    char* w = (char*)d_ws;
    unsigned int* cnt           = (unsigned int*)(w + 0);                    // 16 B
    float* rowstats             = (float*)(w + 256);                         // 128000 B
    unsigned long long* keys    = (unsigned long long*)(w + 128256);         // 524288 B
    unsigned long long* selkeys = (unsigned long long*)(w + 652544);         // 65536 B
    float* cb                   = (float*)(w + 718080);                      // 131072 B
    float* ob                   = (float*)(w + 849152);                      // 131072 B
    float* sc                   = (float*)(w + 980224);                      // 32768 B
    int* lab                    = (int*)(w + 1012992);                       // 32768 B
    unsigned long long* cvw     = (unsigned long long*)(w + 1045760);        // 1024 B
    unsigned long long* M       = (unsigned long long*)(w + 1046784);        // 2097152 B
    (void)ws_size; (void)in_sizes; (void)n_in; (void)out_size;

    hipMemsetAsync(cnt, 0, Bn * sizeof(unsigned int), stream);

    rowstats_k<<<(Bn * Nn) / 4, 256, 0, stream>>>(logits, rowstats);
    cand_k<<<(Bn * Nn * FGC + 255) / 256, 256, 0, stream>>>(logits, regr, props, rowstats, keys, cnt);
    sort_k<<<Bn, 1024, 0, stream>>>(keys, cnt, selkeys);
    select_k<<<(Bn * MSEL) / 256, 256, 0, stream>>>(selkeys, props, regr, cb, ob, sc, lab, cvw);
    nmsmat_k<<<Bn * 32, 256, 0, stream>>>(ob, M);
    scan_k<<<Bn, 64, 0, stream>>>(M, cvw, cb, sc, lab, out);
    assign_k<<<dim3((Nn + Gn + 255) / 256, Bn), 256, 0, stream>>>(props, gtb, gtl, out);
}

// Round 3
// 177.164 us; speedup vs baseline: 5.3318x; 2.7468x over previous
//
#include <hip/hip_runtime.h>
#include <cstdint>
#include <cstddef>

// ---- problem constants (match reference) ----
#define Bn   4
#define Nn   4000
#define Gn   64
#define Cn   91
#define FGC  90          // C-1 foreground classes
#define NSEG 64          // counter segments per image (atomic spreading)
#define CAPSEG 256       // key capacity per segment
#define CAPC (NSEG*CAPSEG)  // 16384 per image (V ~ 8K expected)
#define MSEL 2048        // PRE_NMS_TOPK
#define DETK 100

__device__ __constant__ float kW = 1333.0f;
__device__ __constant__ float kH = 800.0f;
#define XCLIP 4.135166556742356f   // log(1000/16)
#define OFFMUL 1334.0f             // max(W,H)+1

// output layout (floats)
#define OUT_DET  0
#define OUT_REG  (Bn*DETK*5)                         // 2000
#define OUT_LBL  (OUT_REG + Bn*(Nn+Gn)*4)            // 67024
#define OUT_DETL (OUT_LBL + Bn*(Nn+Gn))              // 83280

// ---------------- decode helper (must be bit-identical between kernels) ----------------
__device__ __forceinline__ void decode_box(float4 p, float4 d,
                                           float& bx1, float& by1, float& bx2, float& by2) {
    float pw = p.z - p.x, ph = p.w - p.y;
    float px = p.x + 0.5f * pw, py = p.y + 0.5f * ph;
    float dx = d.x / 10.0f, dy = d.y / 10.0f;
    float dw = fminf(d.z / 5.0f, XCLIP), dh = fminf(d.w / 5.0f, XCLIP);
    float cx = dx * pw + px, cy = dy * ph + py;
    float w = expf(dw) * pw, h = expf(dh) * ph;
    bx1 = fminf(fmaxf(cx - 0.5f * w, 0.0f), kW);
    by1 = fminf(fmaxf(cy - 0.5f * h, 0.0f), kH);
    bx2 = fminf(fmaxf(cx + 0.5f * w, 0.0f), kW);
    by2 = fminf(fmaxf(cy + 0.5f * h, 0.0f), kH);
}

// ---------------- kernel 1: fused softmax + candidate compaction ----------------
// One wave per row: in-register softmax stats (same reduction order as before),
// each lane tests class=lane and class=lane+64, appends valid candidates to a
// per-block counter segment via one wave-aggregated atomic.
__global__ __launch_bounds__(256) void fused_cand_k(const float* __restrict__ logits,
                                                    const float* __restrict__ regr,
                                                    const float* __restrict__ props,
                                                    unsigned long long* __restrict__ keys,
                                                    unsigned int* __restrict__ cnt) {
    int wave = threadIdx.x >> 6, lane = threadIdx.x & 63;
    int blk = blockIdx.x;                 // [0, 4000); 1000 blocks per image
    int row = blk * 4 + wave;             // [0, B*N)
    int b = blk / 1000;
    int n = row - b * Nn;
    const float* z = logits + (size_t)row * Cn;
    float v0 = z[lane];
    bool has1 = (lane + 64) < Cn;         // lane < 27
    float v1 = has1 ? z[lane + 64] : -INFINITY;
    float m = fmaxf(v0, v1);
    #pragma unroll
    for (int o = 32; o; o >>= 1) m = fmaxf(m, __shfl_xor(m, o));
    float e = expf(v0 - m) + (has1 ? expf(v1 - m) : 0.0f);
    #pragma unroll
    for (int o = 32; o; o >>= 1) e += __shfl_xor(e, o);

    float s0 = expf(v0 - m) / e;
    float s1 = has1 ? (expf(v1 - m) / e) : 0.0f;
    bool valid0 = (lane >= 1) && (s0 > 0.05f);
    bool valid1 = has1 && (s1 > 0.05f);

    float4 p = ((const float4*)props)[row];
    unsigned long long key0 = 0, key1 = 0;
    if (valid0) {
        int c = lane;
        float4 d = ((const float4*)regr)[(size_t)row * Cn + c];
        float bx1, by1, bx2, by2;
        decode_box(p, d, bx1, by1, bx2, by2);
        valid0 = (bx2 - bx1 >= 0.01f) && (by2 - by1 >= 0.01f);
        unsigned idx = (unsigned)(n * FGC + c - 1);
        key0 = ((unsigned long long)__float_as_uint(s0) << 32) | (unsigned long long)(~idx);
    }
    if (valid1) {
        int c = lane + 64;
        float4 d = ((const float4*)regr)[(size_t)row * Cn + c];
        float bx1, by1, bx2, by2;
        decode_box(p, d, bx1, by1, bx2, by2);
        valid1 = (bx2 - bx1 >= 0.01f) && (by2 - by1 >= 0.01f);
        unsigned idx = (unsigned)(n * FGC + c - 1);
        key1 = ((unsigned long long)__float_as_uint(s1) << 32) | (unsigned long long)(~idx);
    }
    unsigned long long m0 = __ballot(valid0), m1 = __ballot(valid1);
    unsigned n0 = (unsigned)__popcll(m0);
    unsigned ntot = n0 + (unsigned)__popcll(m1);
    if (ntot) {
        int seg = b * NSEG + (blk & (NSEG - 1));
        unsigned base = 0;
        if (lane == 0) base = atomicAdd(&cnt[seg], ntot);
        base = __shfl(base, 0);
        unsigned long long lmask = (lane == 63) ? ~0ull >> 1 : ((1ull << lane) - 1);
        size_t segbase = (size_t)seg * CAPSEG;   // seg already includes image offset
        if (valid0) {
            unsigned pos = base + (unsigned)__popcll(m0 & lmask);
            if (pos < CAPSEG) keys[segbase + pos] = key0;
        }
        if (valid1) {
            unsigned pos = base + n0 + (unsigned)__popcll(m1 & lmask);
            if (pos < CAPSEG) keys[segbase + pos] = key1;
        }
    }
}

// ---------------- kernel 3: histogram-select top-2048 superset, sort it ----------------
// Score bits are positive floats in (0.05, 1] -> uint-monotonic. Bucket by
// (bits - 0x3D400000) >> 12 (9216 buckets). Select all buckets above the one
// containing the 2048th-largest key, plus that whole bucket (superset, n2 ~ 2050),
// scatter into 4096-slot LDS (zero pad), pair-indexed bitonic sort descending,
// emit first 2048. 8192-wide path if a pathological tie cluster makes n2 > 4096
// (cannot occur with these inputs; correctness path only).
#define NB 9216
#define SBIAS 0x3D400000u

__global__ __launch_bounds__(1024) void sort_k(const unsigned long long* __restrict__ keys,
                                               const unsigned int* __restrict__ cnt,
                                               unsigned long long* __restrict__ selkeys) {
    __shared__ unsigned hist[NB];                  // 36 KiB
    __shared__ unsigned soff[NB];                  // 36 KiB (becomes scatter cursor)
    __shared__ unsigned cs[1024];                  // 4 KiB
    __shared__ unsigned long long sk[8192];        // 64 KiB
    __shared__ unsigned scnt[NSEG];
    __shared__ int sT; __shared__ unsigned sn2;
    int b = blockIdx.x, tid = threadIdx.x;

    for (int h = tid; h < NB; h += 1024) hist[h] = 0;
    if (tid < NSEG) {
        unsigned c = cnt[b * NSEG + tid];
        scnt[tid] = c > CAPSEG ? CAPSEG : c;
    }
    if (tid == 0) { sT = NB; sn2 = 0; }
    __syncthreads();
    unsigned V = 0;
    #pragma unroll
    for (int s2 = 0; s2 < NSEG; ++s2) V += scnt[s2];
    unsigned K2 = V < MSEL ? V : MSEL;
    if (K2 == 0) {                                 // no candidates: emit zeros
        for (int s = tid; s < MSEL; s += 1024) selkeys[b * MSEL + s] = 0ull;
        return;
    }
    for (unsigned g = tid; g < CAPC; g += 1024) {
        unsigned seg = g >> 8, s = g & (CAPSEG - 1);
        if (s < scnt[seg]) {
            unsigned sb = (unsigned)(keys[(size_t)b * CAPC + g] >> 32);
            unsigned h = (sb - SBIAS) >> 12; if (h > NB - 1) h = NB - 1;
            atomicAdd(&hist[h], 1u);
        }
    }
    __syncthreads();
    // per-thread chunk sums (9 buckets each), suffix-scan chunks, then per-bucket
    unsigned csum = 0;
    #pragma unroll
    for (int q = 0; q < 9; ++q) csum += hist[tid * 9 + q];
    cs[tid] = csum; __syncthreads();
    for (int off = 1; off < 1024; off <<= 1) {
        unsigned v = (tid + off < 1024) ? cs[tid + off] : 0u; __syncthreads();
        cs[tid] += v; __syncthreads();
    }
    unsigned run = cs[tid] - csum;                 // keys in buckets of higher chunks
    #pragma unroll
    for (int q = 8; q >= 0; --q) { soff[tid * 9 + q] = run; run += hist[tid * 9 + q]; }
    __syncthreads();
    // find pivot bucket T: soff[T] < K2 <= soff[T]+hist[T]
    #pragma unroll
    for (int q = 0; q < 9; ++q) {
        int h = tid * 9 + q;
        unsigned lo = soff[h], hi = lo + hist[h];
        if (lo < K2 && K2 <= hi) { sT = h; sn2 = hi; }
    }
    __syncthreads();
    int T = sT; unsigned n2 = sn2;
    unsigned P = (n2 <= 4096u) ? 4096u : 8192u;
    for (unsigned s = tid; s < P; s += 1024) sk[s] = 0ull;
    __syncthreads();
    for (unsigned g = tid; g < CAPC; g += 1024) {
        unsigned seg = g >> 8, s = g & (CAPSEG - 1);
        if (s < scnt[seg]) {
            unsigned long long key = keys[(size_t)b * CAPC + g];
            unsigned sb = (unsigned)(key >> 32);
            unsigned h = (sb - SBIAS) >> 12; if (h > NB - 1) h = NB - 1;
            if ((int)h >= T) { unsigned pos = atomicAdd(&soff[h], 1u); if (pos < P) sk[pos] = key; }
        }
    }
    __syncthreads();
    // pair-indexed bitonic sort, descending, P elements
    for (unsigned k = 2; k <= P; k <<= 1) {
        for (unsigned j = k >> 1; j > 0; j >>= 1) {
            for (unsigned p = tid; p < (P >> 1); p += 1024) {
                unsigned s = ((p & ~(j - 1)) << 1) | (p & (j - 1));
                unsigned l = s | j;
                unsigned long long a = sk[s], c2 = sk[l];
                bool descSeg = ((s & k) == 0);
                bool sw = descSeg ? (a < c2) : (a > c2);
                if (sw) { sk[s] = c2; sk[l] = a; }
            }
            __syncthreads();
        }
    }
    for (int s = tid; s < MSEL; s += 1024) selkeys[b * MSEL + s] = sk[s];
}

// ---------------- kernel 4: materialize selected candidates ----------------
__global__ __launch_bounds__(256) void select_k(const unsigned long long* __restrict__ selkeys,
                                                const float* __restrict__ props,
                                                const float* __restrict__ regr,
                                                float* __restrict__ cb, float* __restrict__ ob,
                                                float* __restrict__ sc, int* __restrict__ lab,
                                                unsigned long long* __restrict__ cvw) {
    int t = blockIdx.x * 256 + threadIdx.x;        // B*2048
    if (t >= Bn * MSEL) return;
    int b = t >> 11;
    unsigned long long key = selkeys[t];
    float bx1 = 0, by1 = 0, bx2 = 0, by2 = 0, score = 0;
    int c = 0; unsigned valid = 0;
    if ((key >> 32) != 0ull) {
        valid = 1;
        unsigned idx = ~(unsigned)key;
        int n = idx / FGC, cm1 = idx - n * FGC;
        c = cm1 + 1;
        score = __uint_as_float((unsigned)(key >> 32));
        int row = b * Nn + n;
        float4 p = ((const float4*)props)[row];
        float4 d = ((const float4*)regr)[(size_t)row * Cn + c];
        decode_box(p, d, bx1, by1, bx2, by2);
    }
    float off = (float)c * OFFMUL;
    cb[t * 4 + 0] = bx1; cb[t * 4 + 1] = by1; cb[t * 4 + 2] = bx2; cb[t * 4 + 3] = by2;
    ob[t * 4 + 0] = bx1 + off; ob[t * 4 + 1] = by1 + off;
    ob[t * 4 + 2] = bx2 + off; ob[t * 4 + 3] = by2 + off;
    sc[t] = score; lab[t] = c;
    unsigned long long bw = __ballot(valid != 0u); // pack keep-init words here
    if ((t & 63) == 0) cvw[t >> 6] = bw;
}

// ---------------- kernel 5: suppression bitmask matrix M[b][i][w] ----------------
__global__ __launch_bounds__(256) void nmsmat_k(const float* __restrict__ ob,
                                                unsigned long long* __restrict__ M) {
    __shared__ float4 sb[MSEL];                    // 32 KiB
    int b = blockIdx.x >> 5, chunk = blockIdx.x & 31;   // 32 chunks of 64 rows
    const float4* obf4 = (const float4*)(ob + (size_t)b * MSEL * 4);
    for (int s = threadIdx.x; s < MSEL; s += 256) sb[s] = obf4[s];
    __syncthreads();
    int w = threadIdx.x & 31, i0 = threadIdx.x >> 5;    // i0 in 0..7
    #pragma unroll 1
    for (int r = 0; r < 8; ++r) {
        int i = chunk * 64 + r * 8 + i0;
        float4 bi = sb[i];
        float areai = (bi.z - bi.x) * (bi.w - bi.y);
        unsigned long long bits = 0ull;
        for (int tt = 0; tt < 64; ++tt) {
            int j = w * 64 + tt;
            float4 bj = sb[j];
            float xx1 = fmaxf(bi.x, bj.x), yy1 = fmaxf(bi.y, bj.y);
            float xx2 = fminf(bi.z, bj.z), yy2 = fminf(bi.w, bj.w);
            float iw = fmaxf(xx2 - xx1, 0.0f), ih = fmaxf(yy2 - yy1, 0.0f);
            float inter = iw * ih;
            float areaj = (bj.z - bj.x) * (bj.w - bj.y);
            float iou = inter / (areai + areaj - inter);   // NaN>0.5 is false: matches JAX
            if ((iou > 0.5f) && (j > i)) bits |= (1ull << tt);
        }
        M[((size_t)b * MSEL + i) * 32 + w] = bits;
    }
}

// ---------------- kernel 6: sequential greedy scan (one wave per image) + det output ----------------
// Bit broadcast via v_readlane (VALU, no LDS); early exit once 100 candidates
// are kept (output only uses the first DETK kept; keep determination is in
// scan order, so ranks < 100 are final at that point).
__global__ __launch_bounds__(64) void scan_k(const unsigned long long* __restrict__ M,
                                             const unsigned long long* __restrict__ cvw,
                                             const float* __restrict__ cb,
                                             const float* __restrict__ sc,
                                             const int* __restrict__ lab,
                                             float* __restrict__ out) {
    int b = blockIdx.x, lane = threadIdx.x;
    const bool ld = lane < 32;
    unsigned long long keep = ld ? cvw[b * 32 + lane] : 0ull;
    unsigned kLo = (unsigned)keep, kHi = (unsigned)(keep >> 32);
    __shared__ int keptIdx[DETK];
    const unsigned long long* Mb = M + (size_t)b * MSEL * 32;
    int kcount = 0;                                 // wave-uniform (tests come from readlane)
    unsigned long long Abuf[16], Bbuf[16];
    #pragma unroll
    for (int k = 0; k < 16; ++k) Abuf[k] = ld ? Mb[(size_t)k * 32 + lane] : 0ull;
    for (int g = 0; g < 128; g += 2) {
        #pragma unroll
        for (int k = 0; k < 16; ++k)
            Bbuf[k] = ld ? Mb[(size_t)((g + 1) * 16 + k) * 32 + lane] : 0ull;
        {
            int base = g * 16;
            int rl = base >> 6, sh = base & 31;     // uniform within group
            unsigned half = (base >> 5) & 1;
            #pragma unroll
            for (int k = 0; k < 16; ++k) {
                unsigned kw = half ? kHi : kLo;
                unsigned bitv = (__builtin_amdgcn_readlane(kw, rl) >> (sh + k)) & 1u;
                if (bitv) {
                    unsigned long long m = Abuf[k];
                    kLo &= ~(unsigned)m; kHi &= ~(unsigned)(m >> 32);
                    if (kcount < DETK && lane == 0) keptIdx[kcount] = base + k;
                    ++kcount;
                }
            }
        }
        if (kcount >= DETK) break;
        if (g + 2 < 128) {
            #pragma unroll
            for (int k = 0; k < 16; ++k)
                Abuf[k] = ld ? Mb[(size_t)((g + 2) * 16 + k) * 32 + lane] : 0ull;
        }
        {
            int base = (g + 1) * 16;
            int rl = base >> 6, sh = base & 31;
            unsigned half = (base >> 5) & 1;
            #pragma unroll
            for (int k = 0; k < 16; ++k) {
                unsigned kw = half ? kHi : kLo;
                unsigned bitv = (__builtin_amdgcn_readlane(kw, rl) >> (sh + k)) & 1u;
                if (bitv) {
                    unsigned long long m = Bbuf[k];
                    kLo &= ~(unsigned)m; kHi &= ~(unsigned)(m >> 32);
                    if (kcount < DETK && lane == 0) keptIdx[kcount] = base + k;
                    ++kcount;
                }
            }
        }
        if (kcount >= DETK) break;
    }
    __syncthreads();                                // lgkmcnt drain for keptIdx
    int kept100 = kcount < DETK ? kcount : DETK;
    for (int r = lane; r < kept100; r += 64) {
        int i = keptIdx[r];
        int slot = b * MSEL + i;
        float* dr = out + OUT_DET + ((size_t)b * DETK + r) * 5;
        dr[0] = cb[slot * 4 + 0]; dr[1] = cb[slot * 4 + 1];
        dr[2] = cb[slot * 4 + 2]; dr[3] = cb[slot * 4 + 3];
        dr[4] = sc[slot];
        out[OUT_DETL + b * DETK + r] = (float)lab[slot];
    }
    for (int r = kept100 + lane; r < DETK; r += 64) {
        float* dr = out + OUT_DET + ((size_t)b * DETK + r) * 5;
        dr[0] = dr[1] = dr[2] = dr[3] = dr[4] = 0.0f;
        out[OUT_DETL + b * DETK + r] = 0.0f;
    }
}

// ---------------- kernel 7: proposal->gt matching, reg_targets + lbl ----------------
__global__ __launch_bounds__(256) void assign_k(const float* __restrict__ props,
                                                const float* __restrict__ gtb,
                                                const int* __restrict__ gtl,
                                                float* __restrict__ out) {
    __shared__ float4 sg[Gn];
    int b = blockIdx.y;
    int p = blockIdx.x * 256 + threadIdx.x;
    if (threadIdx.x < Gn) sg[threadIdx.x] = ((const float4*)(gtb + (size_t)b * Gn * 4))[threadIdx.x];
    __syncthreads();
    if (p >= Nn + Gn) return;
    float4 pb = (p < Nn) ? ((const float4*)(props + (size_t)b * Nn * 4))[p] : sg[p - Nn];
    float areap = (pb.z - pb.x) * (pb.w - pb.y);
    float best = -1.0f; int bi = 0;
    #pragma unroll 4
    for (int g = 0; g < Gn; ++g) {
        float4 gb = sg[g];
        float xx1 = fmaxf(gb.x, pb.x), yy1 = fmaxf(gb.y, pb.y);
        float xx2 = fminf(gb.z, pb.z), yy2 = fminf(gb.w, pb.w);
        float iw = fmaxf(xx2 - xx1, 0.0f), ih = fmaxf(yy2 - yy1, 0.0f);
        float inter = iw * ih;
        float areag = (gb.z - gb.x) * (gb.w - gb.y);
        float iou = inter / (areag + areap - inter);
        if (iou > best) { best = iou; bi = g; }     // strict > : first-max, matches argmax
    }
    float4 gb = sg[bi];
    float pw = pb.z - pb.x, ph = pb.w - pb.y;
    float px = pb.x + 0.5f * pw, py = pb.y + 0.5f * ph;
    float gw = gb.z - gb.x, gh = gb.w - gb.y;
    float gx = gb.x + 0.5f * gw, gy = gb.y + 0.5f * gh;
    float* rr = out + OUT_REG + ((size_t)b * (Nn + Gn) + p) * 4;
    rr[0] = 10.0f * (gx - px) / pw;
    rr[1] = 10.0f * (gy - py) / ph;
    rr[2] = 5.0f * logf(gw / pw);
    rr[3] = 5.0f * logf(gh / ph);
    out[OUT_LBL + (size_t)b * (Nn + Gn) + p] = (best >= 0.5f) ? (float)gtl[b * Gn + bi] : 0.0f;
}

// ---------------- launch ----------------
extern "C" void kernel_launch(void* const* d_in, const int* in_sizes, int n_in,
                              void* d_out, int out_size, void* d_ws, size_t ws_size,
                              hipStream_t stream) {
    const float* props  = (const float*)d_in[0];
    const float* gtb    = (const float*)d_in[1];
    const int*   gtl    = (const int*)d_in[2];
    const float* logits = (const float*)d_in[3];
    const float* regr   = (const float*)d_in[4];
    float* out = (float*)d_out;

    // ws layout
    char* w = (char*)d_ws;
    unsigned int* cnt           = (unsigned int*)(w + 0);                    // 1024 B
    unsigned long long* keys    = (unsigned long long*)(w + 1024);           // 524288 B
    unsigned long long* selkeys = (unsigned long long*)(w + 525312);         // 65536 B
    float* cb                   = (float*)(w + 590848);                      // 131072 B
    float* ob                   = (float*)(w + 721920);                      // 131072 B
    float* sc                   = (float*)(w + 852992);                      // 32768 B
    int* lab                    = (int*)(w + 885760);                        // 32768 B
    unsigned long long* cvw     = (unsigned long long*)(w + 918528);         // 1024 B
    unsigned long long* M       = (unsigned long long*)(w + 919552);         // 2097152 B
    (void)ws_size; (void)in_sizes; (void)n_in; (void)out_size;

    hipMemsetAsync(cnt, 0, Bn * NSEG * sizeof(unsigned int), stream);

    fused_cand_k<<<Bn * Nn / 4, 256, 0, stream>>>(logits, regr, props, keys, cnt);
    sort_k<<<Bn, 1024, 0, stream>>>(keys, cnt, selkeys);
    select_k<<<(Bn * MSEL) / 256, 256, 0, stream>>>(selkeys, props, regr, cb, ob, sc, lab, cvw);
    nmsmat_k<<<Bn * 32, 256, 0, stream>>>(ob, M);
    scan_k<<<Bn, 64, 0, stream>>>(M, cvw, cb, sc, lab, out);
    assign_k<<<dim3((Nn + Gn + 255) / 256, Bn), 256, 0, stream>>>(props, gtb, gtl, out);
}

// Round 4
// 134.019 us; speedup vs baseline: 7.0482x; 1.3219x over previous
//
#include <hip/hip_runtime.h>
#include <cstdint>
#include <cstddef>

// ---- problem constants (match reference) ----
#define Bn   4
#define Nn   4000
#define Gn   64
#define Cn   91
#define FGC  90          // C-1 foreground classes
#define NSEG 64          // counter segments per image (atomic spreading)
#define CAPSEG 256       // key capacity per segment
#define CAPC (NSEG*CAPSEG)  // 16384 per image (V ~ 8K expected)
#define MSEL 2048        // PRE_NMS_TOPK
#define DETK 100

__device__ __constant__ float kW = 1333.0f;
__device__ __constant__ float kH = 800.0f;
#define XCLIP 4.135166556742356f   // log(1000/16)
#define OFFMUL 1334.0f             // max(W,H)+1

// output layout (floats)
#define OUT_DET  0
#define OUT_REG  (Bn*DETK*5)                         // 2000
#define OUT_LBL  (OUT_REG + Bn*(Nn+Gn)*4)            // 67024
#define OUT_DETL (OUT_LBL + Bn*(Nn+Gn))              // 83280

// ---------------- decode helper (must be bit-identical between kernels) ----------------
__device__ __forceinline__ void decode_box(float4 p, float4 d,
                                           float& bx1, float& by1, float& bx2, float& by2) {
    float pw = p.z - p.x, ph = p.w - p.y;
    float px = p.x + 0.5f * pw, py = p.y + 0.5f * ph;
    float dx = d.x / 10.0f, dy = d.y / 10.0f;
    float dw = fminf(d.z / 5.0f, XCLIP), dh = fminf(d.w / 5.0f, XCLIP);
    float cx = dx * pw + px, cy = dy * ph + py;
    float w = expf(dw) * pw, h = expf(dh) * ph;
    bx1 = fminf(fmaxf(cx - 0.5f * w, 0.0f), kW);
    by1 = fminf(fmaxf(cy - 0.5f * h, 0.0f), kH);
    bx2 = fminf(fmaxf(cx + 0.5f * w, 0.0f), kW);
    by2 = fminf(fmaxf(cy + 0.5f * h, 0.0f), kH);
}

// ---------------- kernel 1: fused softmax + candidate compaction ----------------
// One wave per row: in-register softmax stats (same reduction order as before),
// each lane tests class=lane and class=lane+64, appends valid candidates to a
// per-block counter segment via one wave-aggregated atomic.
__global__ __launch_bounds__(256) void fused_cand_k(const float* __restrict__ logits,
                                                    const float* __restrict__ regr,
                                                    const float* __restrict__ props,
                                                    unsigned long long* __restrict__ keys,
                                                    unsigned int* __restrict__ cnt) {
    int wave = threadIdx.x >> 6, lane = threadIdx.x & 63;
    int blk = blockIdx.x;                 // [0, 4000); 1000 blocks per image
    int row = blk * 4 + wave;             // [0, B*N)
    int b = blk / 1000;
    int n = row - b * Nn;
    const float* z = logits + (size_t)row * Cn;
    float v0 = z[lane];
    bool has1 = (lane + 64) < Cn;         // lane < 27
    float v1 = has1 ? z[lane + 64] : -INFINITY;
    float m = fmaxf(v0, v1);
    #pragma unroll
    for (int o = 32; o; o >>= 1) m = fmaxf(m, __shfl_xor(m, o));
    float e = expf(v0 - m) + (has1 ? expf(v1 - m) : 0.0f);
    #pragma unroll
    for (int o = 32; o; o >>= 1) e += __shfl_xor(e, o);

    float s0 = expf(v0 - m) / e;
    float s1 = has1 ? (expf(v1 - m) / e) : 0.0f;
    bool valid0 = (lane >= 1) && (s0 > 0.05f);
    bool valid1 = has1 && (s1 > 0.05f);

    float4 p = ((const float4*)props)[row];
    unsigned long long key0 = 0, key1 = 0;
    if (valid0) {
        int c = lane;
        float4 d = ((const float4*)regr)[(size_t)row * Cn + c];
        float bx1, by1, bx2, by2;
        decode_box(p, d, bx1, by1, bx2, by2);
        valid0 = (bx2 - bx1 >= 0.01f) && (by2 - by1 >= 0.01f);
        unsigned idx = (unsigned)(n * FGC + c - 1);
        key0 = ((unsigned long long)__float_as_uint(s0) << 32) | (unsigned long long)(~idx);
    }
    if (valid1) {
        int c = lane + 64;
        float4 d = ((const float4*)regr)[(size_t)row * Cn + c];
        float bx1, by1, bx2, by2;
        decode_box(p, d, bx1, by1, bx2, by2);
        valid1 = (bx2 - bx1 >= 0.01f) && (by2 - by1 >= 0.01f);
        unsigned idx = (unsigned)(n * FGC + c - 1);
        key1 = ((unsigned long long)__float_as_uint(s1) << 32) | (unsigned long long)(~idx);
    }
    unsigned long long m0 = __ballot(valid0), m1 = __ballot(valid1);
    unsigned n0 = (unsigned)__popcll(m0);
    unsigned ntot = n0 + (unsigned)__popcll(m1);
    if (ntot) {
        int seg = b * NSEG + (blk & (NSEG - 1));
        unsigned base = 0;
        if (lane == 0) base = atomicAdd(&cnt[seg], ntot);
        base = __shfl(base, 0);
        unsigned long long lmask = (lane == 63) ? ~0ull >> 1 : ((1ull << lane) - 1);
        size_t segbase = (size_t)seg * CAPSEG;   // seg already includes image offset
        if (valid0) {
            unsigned pos = base + (unsigned)__popcll(m0 & lmask);
            if (pos < CAPSEG) keys[segbase + pos] = key0;
        }
        if (valid1) {
            unsigned pos = base + n0 + (unsigned)__popcll(m1 & lmask);
            if (pos < CAPSEG) keys[segbase + pos] = key1;
        }
    }
}

// ---------------- kernel 3: histogram-select top-2048 superset, sort it ----------------
// Score bits are positive floats in (0.05, 1] -> uint-monotonic. Bucket by
// (bits - 0x3D400000) >> 12 (9216 buckets). Select all buckets above the one
// containing the 2048th-largest key, plus that whole bucket (superset, n2 ~ 2050),
// scatter into 4096-slot LDS (zero pad), pair-indexed bitonic sort descending,
// emit first 2048. 8192-wide path if a pathological tie cluster makes n2 > 4096
// (cannot occur with these inputs; correctness path only).
#define NB 9216
#define SBIAS 0x3D400000u

__global__ __launch_bounds__(1024) void sort_k(const unsigned long long* __restrict__ keys,
                                               const unsigned int* __restrict__ cnt,
                                               unsigned long long* __restrict__ selkeys) {
    __shared__ unsigned hist[NB];                  // 36 KiB
    __shared__ unsigned soff[NB];                  // 36 KiB (becomes scatter cursor)
    __shared__ unsigned cs[1024];                  // 4 KiB
    __shared__ unsigned long long sk[8192];        // 64 KiB
    __shared__ unsigned scnt[NSEG];
    __shared__ int sT; __shared__ unsigned sn2;
    int b = blockIdx.x, tid = threadIdx.x;

    for (int h = tid; h < NB; h += 1024) hist[h] = 0;
    if (tid < NSEG) {
        unsigned c = cnt[b * NSEG + tid];
        scnt[tid] = c > CAPSEG ? CAPSEG : c;
    }
    if (tid == 0) { sT = NB; sn2 = 0; }
    __syncthreads();
    unsigned V = 0;
    #pragma unroll
    for (int s2 = 0; s2 < NSEG; ++s2) V += scnt[s2];
    unsigned K2 = V < MSEL ? V : MSEL;
    if (K2 == 0) {                                 // no candidates: emit zeros
        for (int s = tid; s < MSEL; s += 1024) selkeys[b * MSEL + s] = 0ull;
        return;
    }
    for (unsigned g = tid; g < CAPC; g += 1024) {
        unsigned seg = g >> 8, s = g & (CAPSEG - 1);
        if (s < scnt[seg]) {
            unsigned sb = (unsigned)(keys[(size_t)b * CAPC + g] >> 32);
            unsigned h = (sb - SBIAS) >> 12; if (h > NB - 1) h = NB - 1;
            atomicAdd(&hist[h], 1u);
        }
    }
    __syncthreads();
    // per-thread chunk sums (9 buckets each), suffix-scan chunks, then per-bucket
    unsigned csum = 0;
    #pragma unroll
    for (int q = 0; q < 9; ++q) csum += hist[tid * 9 + q];
    cs[tid] = csum; __syncthreads();
    for (int off = 1; off < 1024; off <<= 1) {
        unsigned v = (tid + off < 1024) ? cs[tid + off] : 0u; __syncthreads();
        cs[tid] += v; __syncthreads();
    }
    unsigned run = cs[tid] - csum;                 // keys in buckets of higher chunks
    #pragma unroll
    for (int q = 8; q >= 0; --q) { soff[tid * 9 + q] = run; run += hist[tid * 9 + q]; }
    __syncthreads();
    // find pivot bucket T: soff[T] < K2 <= soff[T]+hist[T]
    #pragma unroll
    for (int q = 0; q < 9; ++q) {
        int h = tid * 9 + q;
        unsigned lo = soff[h], hi = lo + hist[h];
        if (lo < K2 && K2 <= hi) { sT = h; sn2 = hi; }
    }
    __syncthreads();
    int T = sT; unsigned n2 = sn2;
    unsigned P = (n2 <= 4096u) ? 4096u : 8192u;
    for (unsigned s = tid; s < P; s += 1024) sk[s] = 0ull;
    __syncthreads();
    for (unsigned g = tid; g < CAPC; g += 1024) {
        unsigned seg = g >> 8, s = g & (CAPSEG - 1);
        if (s < scnt[seg]) {
            unsigned long long key = keys[(size_t)b * CAPC + g];
            unsigned sb = (unsigned)(key >> 32);
            unsigned h = (sb - SBIAS) >> 12; if (h > NB - 1) h = NB - 1;
            if ((int)h >= T) { unsigned pos = atomicAdd(&soff[h], 1u); if (pos < P) sk[pos] = key; }
        }
    }
    __syncthreads();
    // pair-indexed bitonic sort, descending, P elements
    for (unsigned k = 2; k <= P; k <<= 1) {
        for (unsigned j = k >> 1; j > 0; j >>= 1) {
            for (unsigned p = tid; p < (P >> 1); p += 1024) {
                unsigned s = ((p & ~(j - 1)) << 1) | (p & (j - 1));
                unsigned l = s | j;
                unsigned long long a = sk[s], c2 = sk[l];
                bool descSeg = ((s & k) == 0);
                bool sw = descSeg ? (a < c2) : (a > c2);
                if (sw) { sk[s] = c2; sk[l] = a; }
            }
            __syncthreads();
        }
    }
    for (int s = tid; s < MSEL; s += 1024) selkeys[b * MSEL + s] = sk[s];
}

// ---------------- kernel 4: materialize selected candidates ----------------
__global__ __launch_bounds__(256) void select_k(const unsigned long long* __restrict__ selkeys,
                                                const float* __restrict__ props,
                                                const float* __restrict__ regr,
                                                float* __restrict__ cb, float* __restrict__ ob,
                                                float* __restrict__ sc, int* __restrict__ lab,
                                                unsigned long long* __restrict__ cvw) {
    int t = blockIdx.x * 256 + threadIdx.x;        // B*2048
    if (t >= Bn * MSEL) return;
    int b = t >> 11;
    unsigned long long key = selkeys[t];
    float bx1 = 0, by1 = 0, bx2 = 0, by2 = 0, score = 0;
    int c = 0; unsigned valid = 0;
    if ((key >> 32) != 0ull) {
        valid = 1;
        unsigned idx = ~(unsigned)key;
        int n = idx / FGC, cm1 = idx - n * FGC;
        c = cm1 + 1;
        score = __uint_as_float((unsigned)(key >> 32));
        int row = b * Nn + n;
        float4 p = ((const float4*)props)[row];
        float4 d = ((const float4*)regr)[(size_t)row * Cn + c];
        decode_box(p, d, bx1, by1, bx2, by2);
    }
    float off = (float)c * OFFMUL;
    cb[t * 4 + 0] = bx1; cb[t * 4 + 1] = by1; cb[t * 4 + 2] = bx2; cb[t * 4 + 3] = by2;
    ob[t * 4 + 0] = bx1 + off; ob[t * 4 + 1] = by1 + off;
    ob[t * 4 + 2] = bx2 + off; ob[t * 4 + 3] = by2 + off;
    sc[t] = score; lab[t] = c;
    unsigned long long bw = __ballot(valid != 0u); // pack keep-init words here
    if ((t & 63) == 0) cvw[t >> 6] = bw;
}

// ---------------- kernel 5: suppression bitmask matrix M[b][i][w] ----------------
// One block = 256 rows (i) x one 64-col chunk (w). j-boxes in LDS, inner-loop
// reads are wave-uniform (broadcast, zero bank conflicts). Row box is a
// coalesced global load (L2-hot). Chunks fully below the diagonal are zero.
__global__ __launch_bounds__(256) void nmsmat_k(const float* __restrict__ ob,
                                                unsigned long long* __restrict__ M) {
    int blk = blockIdx.x;                 // Bn * 8 * 32
    int b = blk >> 8, rc = (blk >> 5) & 7, w = blk & 31;
    int i = rc * 256 + threadIdx.x;
    size_t mi = ((size_t)b * MSEL + i) * 32 + w;
    if (w * 64 + 63 <= rc * 256) {        // all j <= min i: bits provably zero
        M[mi] = 0ull;                     // must write (ws is poisoned)
        return;
    }
    __shared__ float4 sj[64];
    const float4* obf4 = (const float4*)(ob + (size_t)b * MSEL * 4);
    if (threadIdx.x < 64) sj[threadIdx.x] = obf4[w * 64 + threadIdx.x];
    __syncthreads();
    float4 bi = obf4[i];
    float areai = (bi.z - bi.x) * (bi.w - bi.y);
    unsigned long long bits = 0ull;
    #pragma unroll 16
    for (int tt = 0; tt < 64; ++tt) {
        int j = w * 64 + tt;
        float4 bj = sj[tt];               // wave-uniform LDS read -> broadcast
        float xx1 = fmaxf(bi.x, bj.x), yy1 = fmaxf(bi.y, bj.y);
        float xx2 = fminf(bi.z, bj.z), yy2 = fminf(bi.w, bj.w);
        float iw = fmaxf(xx2 - xx1, 0.0f), ih = fmaxf(yy2 - yy1, 0.0f);
        float inter = iw * ih;
        float areaj = (bj.z - bj.x) * (bj.w - bj.y);
        float iou = inter / (areai + areaj - inter);   // NaN>0.5 is false: matches JAX
        if ((iou > 0.5f) && (j > i)) bits |= (1ull << tt);
    }
    M[mi] = bits;
}

// ---------------- kernel 6: sequential greedy scan (one wave per image) + det output ----------------
// Bit broadcast via v_readlane (VALU, no LDS); early exit once 100 candidates
// are kept (output only uses the first DETK kept; keep determination is in
// scan order, so ranks < 100 are final at that point).
__global__ __launch_bounds__(64) void scan_k(const unsigned long long* __restrict__ M,
                                             const unsigned long long* __restrict__ cvw,
                                             const float* __restrict__ cb,
                                             const float* __restrict__ sc,
                                             const int* __restrict__ lab,
                                             float* __restrict__ out) {
    int b = blockIdx.x, lane = threadIdx.x;
    const bool ld = lane < 32;
    unsigned long long keep = ld ? cvw[b * 32 + lane] : 0ull;
    unsigned kLo = (unsigned)keep, kHi = (unsigned)(keep >> 32);
    __shared__ int keptIdx[DETK];
    const unsigned long long* Mb = M + (size_t)b * MSEL * 32;
    int kcount = 0;                                 // wave-uniform (tests come from readlane)
    unsigned long long Abuf[16], Bbuf[16];
    #pragma unroll
    for (int k = 0; k < 16; ++k) Abuf[k] = ld ? Mb[(size_t)k * 32 + lane] : 0ull;
    for (int g = 0; g < 128; g += 2) {
        #pragma unroll
        for (int k = 0; k < 16; ++k)
            Bbuf[k] = ld ? Mb[(size_t)((g + 1) * 16 + k) * 32 + lane] : 0ull;
        {
            int base = g * 16;
            int rl = base >> 6, sh = base & 31;     // uniform within group
            unsigned half = (base >> 5) & 1;
            #pragma unroll
            for (int k = 0; k < 16; ++k) {
                unsigned kw = half ? kHi : kLo;
                unsigned bitv = (__builtin_amdgcn_readlane(kw, rl) >> (sh + k)) & 1u;
                if (bitv) {
                    unsigned long long m = Abuf[k];
                    kLo &= ~(unsigned)m; kHi &= ~(unsigned)(m >> 32);
                    if (kcount < DETK && lane == 0) keptIdx[kcount] = base + k;
                    ++kcount;
                }
            }
        }
        if (kcount >= DETK) break;
        if (g + 2 < 128) {
            #pragma unroll
            for (int k = 0; k < 16; ++k)
                Abuf[k] = ld ? Mb[(size_t)((g + 2) * 16 + k) * 32 + lane] : 0ull;
        }
        {
            int base = (g + 1) * 16;
            int rl = base >> 6, sh = base & 31;
            unsigned half = (base >> 5) & 1;
            #pragma unroll
            for (int k = 0; k < 16; ++k) {
                unsigned kw = half ? kHi : kLo;
                unsigned bitv = (__builtin_amdgcn_readlane(kw, rl) >> (sh + k)) & 1u;
                if (bitv) {
                    unsigned long long m = Bbuf[k];
                    kLo &= ~(unsigned)m; kHi &= ~(unsigned)(m >> 32);
                    if (kcount < DETK && lane == 0) keptIdx[kcount] = base + k;
                    ++kcount;
                }
            }
        }
        if (kcount >= DETK) break;
    }
    __syncthreads();                                // lgkmcnt drain for keptIdx
    int kept100 = kcount < DETK ? kcount : DETK;
    for (int r = lane; r < kept100; r += 64) {
        int i = keptIdx[r];
        int slot = b * MSEL + i;
        float* dr = out + OUT_DET + ((size_t)b * DETK + r) * 5;
        dr[0] = cb[slot * 4 + 0]; dr[1] = cb[slot * 4 + 1];
        dr[2] = cb[slot * 4 + 2]; dr[3] = cb[slot * 4 + 3];
        dr[4] = sc[slot];
        out[OUT_DETL + b * DETK + r] = (float)lab[slot];
    }
    for (int r = kept100 + lane; r < DETK; r += 64) {
        float* dr = out + OUT_DET + ((size_t)b * DETK + r) * 5;
        dr[0] = dr[1] = dr[2] = dr[3] = dr[4] = 0.0f;
        out[OUT_DETL + b * DETK + r] = 0.0f;
    }
}

// ---------------- kernel 7: proposal->gt matching, reg_targets + lbl ----------------
__global__ __launch_bounds__(256) void assign_k(const float* __restrict__ props,
                                                const float* __restrict__ gtb,
                                                const int* __restrict__ gtl,
                                                float* __restrict__ out) {
    __shared__ float4 sg[Gn];
    int b = blockIdx.y;
    int p = blockIdx.x * 256 + threadIdx.x;
    if (threadIdx.x < Gn) sg[threadIdx.x] = ((const float4*)(gtb + (size_t)b * Gn * 4))[threadIdx.x];
    __syncthreads();
    if (p >= Nn + Gn) return;
    float4 pb = (p < Nn) ? ((const float4*)(props + (size_t)b * Nn * 4))[p] : sg[p - Nn];
    float areap = (pb.z - pb.x) * (pb.w - pb.y);
    float best = -1.0f; int bi = 0;
    #pragma unroll 4
    for (int g = 0; g < Gn; ++g) {
        float4 gb = sg[g];
        float xx1 = fmaxf(gb.x, pb.x), yy1 = fmaxf(gb.y, pb.y);
        float xx2 = fminf(gb.z, pb.z), yy2 = fminf(gb.w, pb.w);
        float iw = fmaxf(xx2 - xx1, 0.0f), ih = fmaxf(yy2 - yy1, 0.0f);
        float inter = iw * ih;
        float areag = (gb.z - gb.x) * (gb.w - gb.y);
        float iou = inter / (areag + areap - inter);
        if (iou > best) { best = iou; bi = g; }     // strict > : first-max, matches argmax
    }
    float4 gb = sg[bi];
    float pw = pb.z - pb.x, ph = pb.w - pb.y;
    float px = pb.x + 0.5f * pw, py = pb.y + 0.5f * ph;
    float gw = gb.z - gb.x, gh = gb.w - gb.y;
    float gx = gb.x + 0.5f * gw, gy = gb.y + 0.5f * gh;
    float* rr = out + OUT_REG + ((size_t)b * (Nn + Gn) + p) * 4;
    rr[0] = 10.0f * (gx - px) / pw;
    rr[1] = 10.0f * (gy - py) / ph;
    rr[2] = 5.0f * logf(gw / pw);
    rr[3] = 5.0f * logf(gh / ph);
    out[OUT_LBL + (size_t)b * (Nn + Gn) + p] = (best >= 0.5f) ? (float)gtl[b * Gn + bi] : 0.0f;
}

// ---------------- launch ----------------
extern "C" void kernel_launch(void* const* d_in, const int* in_sizes, int n_in,
                              void* d_out, int out_size, void* d_ws, size_t ws_size,
                              hipStream_t stream) {
    const float* props  = (const float*)d_in[0];
    const float* gtb    = (const float*)d_in[1];
    const int*   gtl    = (const int*)d_in[2];
    const float* logits = (const float*)d_in[3];
    const float* regr   = (const float*)d_in[4];
    float* out = (float*)d_out;

    // ws layout
    char* w = (char*)d_ws;
    unsigned int* cnt           = (unsigned int*)(w + 0);                    // 1024 B
    unsigned long long* keys    = (unsigned long long*)(w + 1024);           // 524288 B
    unsigned long long* selkeys = (unsigned long long*)(w + 525312);         // 65536 B
    float* cb                   = (float*)(w + 590848);                      // 131072 B
    float* ob                   = (float*)(w + 721920);                      // 131072 B
    float* sc                   = (float*)(w + 852992);                      // 32768 B
    int* lab                    = (int*)(w + 885760);                        // 32768 B
    unsigned long long* cvw     = (unsigned long long*)(w + 918528);         // 1024 B
    unsigned long long* M       = (unsigned long long*)(w + 919552);         // 2097152 B
    (void)ws_size; (void)in_sizes; (void)n_in; (void)out_size;

    hipMemsetAsync(cnt, 0, Bn * NSEG * sizeof(unsigned int), stream);

    fused_cand_k<<<Bn * Nn / 4, 256, 0, stream>>>(logits, regr, props, keys, cnt);
    sort_k<<<Bn, 1024, 0, stream>>>(keys, cnt, selkeys);
    select_k<<<(Bn * MSEL) / 256, 256, 0, stream>>>(selkeys, props, regr, cb, ob, sc, lab, cvw);
    nmsmat_k<<<Bn * 256, 256, 0, stream>>>(ob, M);
    scan_k<<<Bn, 64, 0, stream>>>(M, cvw, cb, sc, lab, out);
    assign_k<<<dim3((Nn + Gn + 255) / 256, Bn), 256, 0, stream>>>(props, gtb, gtl, out);
}

// Round 5
// 112.652 us; speedup vs baseline: 8.3851x; 1.1897x over previous
//
#include <hip/hip_runtime.h>
#include <cstdint>
#include <cstddef>

// ---- problem constants (match reference) ----
#define Bn   4
#define Nn   4000
#define Gn   64
#define Cn   91
#define FGC  90          // C-1 foreground classes
#define NSEG 64          // counter segments per image (atomic spreading)
#define CAPSEG 256       // key capacity per segment
#define CAPC (NSEG*CAPSEG)  // 16384 per image (V ~ 8K expected)
#define SELCAP 4096      // selected-superset capacity (n2 ~ 2050 expected)
#define MSEL 2048        // PRE_NMS_TOPK
#define DETK 100

__device__ __constant__ float kW = 1333.0f;
__device__ __constant__ float kH = 800.0f;
#define XCLIP 4.135166556742356f   // log(1000/16)
#define OFFMUL 1334.0f             // max(W,H)+1

// score-bit bucketing (uint-monotone for positive floats)
#define NB 9216
#define SBIAS 0x3D400000u

typedef __attribute__((ext_vector_type(2))) unsigned long long u64x2;

// output layout (floats)
#define OUT_DET  0
#define OUT_REG  (Bn*DETK*5)                         // 2000
#define OUT_LBL  (OUT_REG + Bn*(Nn+Gn)*4)            // 67024
#define OUT_DETL (OUT_LBL + Bn*(Nn+Gn))              // 83280

// ---------------- decode helper (must be bit-identical between kernels) ----------------
__device__ __forceinline__ void decode_box(float4 p, float4 d,
                                           float& bx1, float& by1, float& bx2, float& by2) {
    float pw = p.z - p.x, ph = p.w - p.y;
    float px = p.x + 0.5f * pw, py = p.y + 0.5f * ph;
    float dx = d.x / 10.0f, dy = d.y / 10.0f;
    float dw = fminf(d.z / 5.0f, XCLIP), dh = fminf(d.w / 5.0f, XCLIP);
    float cx = dx * pw + px, cy = dy * ph + py;
    float w = expf(dw) * pw, h = expf(dh) * ph;
    bx1 = fminf(fmaxf(cx - 0.5f * w, 0.0f), kW);
    by1 = fminf(fmaxf(cy - 0.5f * h, 0.0f), kH);
    bx2 = fminf(fmaxf(cx + 0.5f * w, 0.0f), kW);
    by2 = fminf(fmaxf(cy + 0.5f * h, 0.0f), kH);
}

__device__ __forceinline__ unsigned score_bucket(unsigned sb) {
    unsigned h = (sb - SBIAS) >> 12;
    return h > (NB - 1) ? (NB - 1) : h;
}

// ---------------- kernel 1: fused softmax + candidate compaction + histogram ----------------
__global__ __launch_bounds__(256) void fused_cand_k(const float* __restrict__ logits,
                                                    const float* __restrict__ regr,
                                                    const float* __restrict__ props,
                                                    unsigned long long* __restrict__ keys,
                                                    unsigned int* __restrict__ cnt,
                                                    unsigned int* __restrict__ hist) {
    int wave = threadIdx.x >> 6, lane = threadIdx.x & 63;
    int blk = blockIdx.x;                 // [0, 4000); 1000 blocks per image
    int row = blk * 4 + wave;             // [0, B*N)
    int b = blk / 1000;
    int n = row - b * Nn;
    const float* z = logits + (size_t)row * Cn;
    float v0 = z[lane];
    bool has1 = (lane + 64) < Cn;         // lane < 27
    float v1 = has1 ? z[lane + 64] : -INFINITY;
    float m = fmaxf(v0, v1);
    #pragma unroll
    for (int o = 32; o; o >>= 1) m = fmaxf(m, __shfl_xor(m, o));
    float e = expf(v0 - m) + (has1 ? expf(v1 - m) : 0.0f);
    #pragma unroll
    for (int o = 32; o; o >>= 1) e += __shfl_xor(e, o);

    float s0 = expf(v0 - m) / e;
    float s1 = has1 ? (expf(v1 - m) / e) : 0.0f;
    bool valid0 = (lane >= 1) && (s0 > 0.05f);
    bool valid1 = has1 && (s1 > 0.05f);

    float4 p = ((const float4*)props)[row];
    unsigned long long key0 = 0, key1 = 0;
    if (valid0) {
        int c = lane;
        float4 d = ((const float4*)regr)[(size_t)row * Cn + c];
        float bx1, by1, bx2, by2;
        decode_box(p, d, bx1, by1, bx2, by2);
        valid0 = (bx2 - bx1 >= 0.01f) && (by2 - by1 >= 0.01f);
        unsigned idx = (unsigned)(n * FGC + c - 1);
        key0 = ((unsigned long long)__float_as_uint(s0) << 32) | (unsigned long long)(~idx);
    }
    if (valid1) {
        int c = lane + 64;
        float4 d = ((const float4*)regr)[(size_t)row * Cn + c];
        float bx1, by1, bx2, by2;
        decode_box(p, d, bx1, by1, bx2, by2);
        valid1 = (bx2 - bx1 >= 0.01f) && (by2 - by1 >= 0.01f);
        unsigned idx = (unsigned)(n * FGC + c - 1);
        key1 = ((unsigned long long)__float_as_uint(s1) << 32) | (unsigned long long)(~idx);
    }
    if (valid0) atomicAdd(&hist[b * NB + score_bucket(__float_as_uint(s0))], 1u);
    if (valid1) atomicAdd(&hist[b * NB + score_bucket(__float_as_uint(s1))], 1u);
    unsigned long long m0 = __ballot(valid0), m1 = __ballot(valid1);
    unsigned n0 = (unsigned)__popcll(m0);
    unsigned ntot = n0 + (unsigned)__popcll(m1);
    if (ntot) {
        int seg = b * NSEG + (blk & (NSEG - 1));
        unsigned base = 0;
        if (lane == 0) base = atomicAdd(&cnt[seg], ntot);
        base = __shfl(base, 0);
        unsigned long long lmask = (lane == 63) ? ~0ull >> 1 : ((1ull << lane) - 1);
        size_t segbase = (size_t)seg * CAPSEG;   // seg already includes image offset
        if (valid0) {
            unsigned pos = base + (unsigned)__popcll(m0 & lmask);
            if (pos < CAPSEG) keys[segbase + pos] = key0;
        }
        if (valid1) {
            unsigned pos = base + n0 + (unsigned)__popcll(m1 & lmask);
            if (pos < CAPSEG) keys[segbase + pos] = key1;
        }
    }
}

// ---------------- kernel 2: pivot (per block, redundant) + compact selected superset ----------------
// Selected = keys in buckets >= T, where T is the bucket containing the K2-th
// largest score (K2 = min(V, 2048)). Every top-2048 key has bucket >= T
// (buckets monotone in score bits), so sel[] is a superset, n2 ~ 2050.
// Append order into sel[] is nondeterministic but rank_k canonicalizes it.
__global__ __launch_bounds__(256) void compact_k(const unsigned long long* __restrict__ keys,
                                                 const unsigned int* __restrict__ cnt,
                                                 const unsigned int* __restrict__ hist,
                                                 unsigned long long* __restrict__ sel,
                                                 unsigned int* __restrict__ cnt2) {
    int b = blockIdx.x >> 4, blk = blockIdx.x & 15;   // 16 blocks/image, 1024 slots each
    int tid = threadIdx.x, lane = tid & 63, wv = tid >> 6;
    __shared__ unsigned wtot[4], wt2[4], sscnt[NSEG];
    __shared__ unsigned sT, sbase;

    // ---- pivot: each thread owns 36 consecutive buckets ----
    const uint4* h4 = (const uint4*)(hist + b * NB);
    unsigned hc[36]; unsigned s = 0;
    #pragma unroll
    for (int q = 0; q < 9; ++q) {
        uint4 t4 = h4[tid * 9 + q];
        hc[q*4+0] = t4.x; hc[q*4+1] = t4.y; hc[q*4+2] = t4.z; hc[q*4+3] = t4.w;
        s += t4.x + t4.y + t4.z + t4.w;
    }
    unsigned x = s;                                   // wave inclusive suffix scan
    #pragma unroll
    for (int o = 1; o < 64; o <<= 1) { unsigned v = __shfl_down(x, o); if (lane + o < 64) x += v; }
    if (lane == 0) wtot[wv] = x;
    if (tid < NSEG) { unsigned c = cnt[b * NSEG + tid]; sscnt[tid] = c > CAPSEG ? CAPSEG : c; }
    __syncthreads();
    unsigned above = 0, total = 0;
    #pragma unroll
    for (int i2 = 0; i2 < 4; ++i2) { unsigned w2 = wtot[i2]; total += w2; if (i2 > wv) above += w2; }
    unsigned K2 = total < MSEL ? total : MSEL;
    if (K2 == 0) return;                              // sel stays 0, cnt2 stays 0 (memset)
    unsigned run = (x - s) + above;                   // # keys in buckets above my chunk
    #pragma unroll
    for (int q = 35; q >= 0; --q) {
        unsigned c = hc[q], lo = run;                 // lo = # keys in buckets > (tid*36+q)
        run += c;
        if (lo < K2 && K2 <= run) sT = (unsigned)(tid * 36 + q);
    }
    __syncthreads();
    unsigned T = sT;

    // ---- selection: 4 slots per thread, block-aggregated append ----
    unsigned long long k0 = 0, k1 = 0, k2 = 0, k3 = 0;
    bool v0 = false, v1 = false, v2 = false, v3 = false;
    {
        int g = blk * 1024 + 0 * 256 + tid; unsigned seg = g >> 8, ss = g & 255;
        if (ss < sscnt[seg]) { unsigned long long k = keys[(size_t)b * CAPC + g];
            if (score_bucket((unsigned)(k >> 32)) >= T) { k0 = k; v0 = true; } }
    }
    {
        int g = blk * 1024 + 1 * 256 + tid; unsigned seg = g >> 8, ss = g & 255;
        if (ss < sscnt[seg]) { unsigned long long k = keys[(size_t)b * CAPC + g];
            if (score_bucket((unsigned)(k >> 32)) >= T) { k1 = k; v1 = true; } }
    }
    {
        int g = blk * 1024 + 2 * 256 + tid; unsigned seg = g >> 8, ss = g & 255;
        if (ss < sscnt[seg]) { unsigned long long k = keys[(size_t)b * CAPC + g];
            if (score_bucket((unsigned)(k >> 32)) >= T) { k2 = k; v2 = true; } }
    }
    {
        int g = blk * 1024 + 3 * 256 + tid; unsigned seg = g >> 8, ss = g & 255;
        if (ss < sscnt[seg]) { unsigned long long k = keys[(size_t)b * CAPC + g];
            if (score_bucket((unsigned)(k >> 32)) >= T) { k3 = k; v3 = true; } }
    }
    unsigned c2 = (unsigned)v0 + (unsigned)v1 + (unsigned)v2 + (unsigned)v3;
    unsigned inc = c2;
    #pragma unroll
    for (int o = 1; o < 64; o <<= 1) { unsigned v = __shfl_up(inc, o); if (lane >= o) inc += v; }
    unsigned excl = inc - c2;
    if (lane == 63) wt2[wv] = inc;
    __syncthreads();
    if (tid == 0) {
        unsigned tot = wt2[0] + wt2[1] + wt2[2] + wt2[3];
        sbase = tot ? atomicAdd(&cnt2[b], tot) : 0u;
    }
    __syncthreads();
    unsigned pos = sbase + excl;
    #pragma unroll
    for (int i2 = 0; i2 < 4; ++i2) if (i2 < wv) pos += wt2[i2];
    unsigned long long* selb = sel + (size_t)b * SELCAP;
    unsigned q0 = pos, q1 = q0 + v0, q2 = q1 + v1, q3 = q2 + v2;
    if (v0 && q0 < SELCAP) selb[q0] = k0;
    if (v1 && q1 < SELCAP) selb[q1] = k1;
    if (v2 && q2 < SELCAP) selb[q2] = k2;
    if (v3 && q3 < SELCAP) selb[q3] = k3;
}

// ---------------- kernel 3: rank selected keys -> sorted top-2048 ----------------
// rank(key) = # selected keys greater (keys unique; non-selected keys are all
// smaller than every selected key, so rank among selected == global rank).
// Block: 64 subjects x 4 waves splitting the comparand range; zero-pads never
// count. Writes selkeys[rank] directly (selkeys pre-zeroed by memset).
__global__ __launch_bounds__(256) void rank_k(const unsigned long long* __restrict__ sel,
                                              const unsigned int* __restrict__ cnt2,
                                              unsigned long long* __restrict__ selkeys) {
    int b = blockIdx.x >> 6, blk = blockIdx.x & 63;   // 64 subject-blocks/image
    unsigned n2 = cnt2[b]; if (n2 > SELCAP) n2 = SELCAP;
    if ((unsigned)(blk * 64) >= n2) return;
    int lane = threadIdx.x & 63, wv = threadIdx.x >> 6;
    int sub = blk * 64 + lane;
    __shared__ __align__(16) unsigned long long skk[SELCAP + 2];
    __shared__ unsigned pc[4][64];
    unsigned n2p = (n2 + 1) & ~1u;
    const unsigned long long* selb = sel + (size_t)b * SELCAP;
    for (unsigned s2 = threadIdx.x; s2 < n2p; s2 += 256)
        skk[s2] = (s2 < n2) ? selb[s2] : 0ull;
    __syncthreads();
    unsigned long long mk = (sub < (int)n2) ? skk[sub] : ~0ull;
    bool act = (sub < (int)n2) && ((mk >> 32) != 0ull);
    unsigned pairs = n2p >> 1;
    unsigned Q = (pairs + 3) >> 2;
    unsigned jb = wv * Q, je = jb + Q; if (je > pairs) je = pairs;
    const u64x2* sk2 = (const u64x2*)skk;
    unsigned cntg = 0;
    for (unsigned j = jb; j < je; ++j) {
        u64x2 kk = sk2[j];
        cntg += (unsigned)(kk.x > mk) + (unsigned)(kk.y > mk);
    }
    pc[wv][lane] = cntg;
    __syncthreads();
    if (wv == 0) {
        unsigned rank = pc[0][lane] + pc[1][lane] + pc[2][lane] + pc[3][lane];
        if (act && rank < MSEL) selkeys[(size_t)b * MSEL + rank] = mk;
    }
}

// ---------------- kernel 4: materialize selected candidates ----------------
__global__ __launch_bounds__(256) void select_k(const unsigned long long* __restrict__ selkeys,
                                                const float* __restrict__ props,
                                                const float* __restrict__ regr,
                                                float* __restrict__ cb, float* __restrict__ ob,
                                                float* __restrict__ sc, int* __restrict__ lab,
                                                unsigned long long* __restrict__ cvw) {
    int t = blockIdx.x * 256 + threadIdx.x;        // B*2048
    if (t >= Bn * MSEL) return;
    int b = t >> 11;
    unsigned long long key = selkeys[t];
    float bx1 = 0, by1 = 0, bx2 = 0, by2 = 0, score = 0;
    int c = 0; unsigned valid = 0;
    if ((key >> 32) != 0ull) {
        valid = 1;
        unsigned idx = ~(unsigned)key;
        int n = idx / FGC, cm1 = idx - n * FGC;
        c = cm1 + 1;
        score = __uint_as_float((unsigned)(key >> 32));
        int row = b * Nn + n;
        float4 p = ((const float4*)props)[row];
        float4 d = ((const float4*)regr)[(size_t)row * Cn + c];
        decode_box(p, d, bx1, by1, bx2, by2);
    }
    float off = (float)c * OFFMUL;
    cb[t * 4 + 0] = bx1; cb[t * 4 + 1] = by1; cb[t * 4 + 2] = bx2; cb[t * 4 + 3] = by2;
    ob[t * 4 + 0] = bx1 + off; ob[t * 4 + 1] = by1 + off;
    ob[t * 4 + 2] = bx2 + off; ob[t * 4 + 3] = by2 + off;
    sc[t] = score; lab[t] = c;
    unsigned long long bw = __ballot(valid != 0u); // pack keep-init words here
    if ((t & 63) == 0) cvw[t >> 6] = bw;
}

// ---------------- kernel 5: suppression bitmask matrix M[b][i][w] ----------------
__global__ __launch_bounds__(256) void nmsmat_k(const float* __restrict__ ob,
                                                unsigned long long* __restrict__ M) {
    int blk = blockIdx.x;                 // Bn * 8 * 32
    int b = blk >> 8, rc = (blk >> 5) & 7, w = blk & 31;
    int i = rc * 256 + threadIdx.x;
    size_t mi = ((size_t)b * MSEL + i) * 32 + w;
    if (w * 64 + 63 <= rc * 256) {        // all j <= min i: bits provably zero
        M[mi] = 0ull;                     // must write (ws is poisoned)
        return;
    }
    __shared__ float4 sj[64];
    const float4* obf4 = (const float4*)(ob + (size_t)b * MSEL * 4);
    if (threadIdx.x < 64) sj[threadIdx.x] = obf4[w * 64 + threadIdx.x];
    __syncthreads();
    float4 bi = obf4[i];
    float areai = (bi.z - bi.x) * (bi.w - bi.y);
    unsigned long long bits = 0ull;
    #pragma unroll 16
    for (int tt = 0; tt < 64; ++tt) {
        int j = w * 64 + tt;
        float4 bj = sj[tt];               // wave-uniform LDS read -> broadcast
        float xx1 = fmaxf(bi.x, bj.x), yy1 = fmaxf(bi.y, bj.y);
        float xx2 = fminf(bi.z, bj.z), yy2 = fminf(bi.w, bj.w);
        float iw = fmaxf(xx2 - xx1, 0.0f), ih = fmaxf(yy2 - yy1, 0.0f);
        float inter = iw * ih;
        float areaj = (bj.z - bj.x) * (bj.w - bj.y);
        float iou = inter / (areai + areaj - inter);   // NaN>0.5 is false: matches JAX
        if ((iou > 0.5f) && (j > i)) bits |= (1ull << tt);
    }
    M[mi] = bits;
}

// ---------------- kernel 6: sequential greedy scan (one wave per image) + det output ----------------
__global__ __launch_bounds__(64) void scan_k(const unsigned long long* __restrict__ M,
                                             const unsigned long long* __restrict__ cvw,
                                             const float* __restrict__ cb,
                                             const float* __restrict__ sc,
                                             const int* __restrict__ lab,
                                             float* __restrict__ out) {
    int b = blockIdx.x, lane = threadIdx.x;
    const bool ld = lane < 32;
    unsigned long long keep = ld ? cvw[b * 32 + lane] : 0ull;
    unsigned kLo = (unsigned)keep, kHi = (unsigned)(keep >> 32);
    __shared__ int keptIdx[DETK];
    const unsigned long long* Mb = M + (size_t)b * MSEL * 32;
    int kcount = 0;                                 // wave-uniform (tests come from readlane)
    unsigned long long Abuf[16], Bbuf[16];
    #pragma unroll
    for (int k = 0; k < 16; ++k) Abuf[k] = ld ? Mb[(size_t)k * 32 + lane] : 0ull;
    for (int g = 0; g < 128; g += 2) {
        #pragma unroll
        for (int k = 0; k < 16; ++k)
            Bbuf[k] = ld ? Mb[(size_t)((g + 1) * 16 + k) * 32 + lane] : 0ull;
        {
            int base = g * 16;
            int rl = base >> 6, sh = base & 31;     // uniform within group
            unsigned half = (base >> 5) & 1;
            #pragma unroll
            for (int k = 0; k < 16; ++k) {
                unsigned kw = half ? kHi : kLo;
                unsigned bitv = (__builtin_amdgcn_readlane(kw, rl) >> (sh + k)) & 1u;
                if (bitv) {
                    unsigned long long m = Abuf[k];
                    kLo &= ~(unsigned)m; kHi &= ~(unsigned)(m >> 32);
                    if (kcount < DETK && lane == 0) keptIdx[kcount] = base + k;
                    ++kcount;
                }
            }
        }
        if (kcount >= DETK) break;
        if (g + 2 < 128) {
            #pragma unroll
            for (int k = 0; k < 16; ++k)
                Abuf[k] = ld ? Mb[(size_t)((g + 2) * 16 + k) * 32 + lane] : 0ull;
        }
        {
            int base = (g + 1) * 16;
            int rl = base >> 6, sh = base & 31;
            unsigned half = (base >> 5) & 1;
            #pragma unroll
            for (int k = 0; k < 16; ++k) {
                unsigned kw = half ? kHi : kLo;
                unsigned bitv = (__builtin_amdgcn_readlane(kw, rl) >> (sh + k)) & 1u;
                if (bitv) {
                    unsigned long long m = Bbuf[k];
                    kLo &= ~(unsigned)m; kHi &= ~(unsigned)(m >> 32);
                    if (kcount < DETK && lane == 0) keptIdx[kcount] = base + k;
                    ++kcount;
                }
            }
        }
        if (kcount >= DETK) break;
    }
    __syncthreads();                                // lgkmcnt drain for keptIdx
    int kept100 = kcount < DETK ? kcount : DETK;
    for (int r = lane; r < kept100; r += 64) {
        int i = keptIdx[r];
        int slot = b * MSEL + i;
        float* dr = out + OUT_DET + ((size_t)b * DETK + r) * 5;
        dr[0] = cb[slot * 4 + 0]; dr[1] = cb[slot * 4 + 1];
        dr[2] = cb[slot * 4 + 2]; dr[3] = cb[slot * 4 + 3];
        dr[4] = sc[slot];
        out[OUT_DETL + b * DETK + r] = (float)lab[slot];
    }
    for (int r = kept100 + lane; r < DETK; r += 64) {
        float* dr = out + OUT_DET + ((size_t)b * DETK + r) * 5;
        dr[0] = dr[1] = dr[2] = dr[3] = dr[4] = 0.0f;
        out[OUT_DETL + b * DETK + r] = 0.0f;
    }
}

// ---------------- kernel 7: proposal->gt matching, reg_targets + lbl ----------------
__global__ __launch_bounds__(256) void assign_k(const float* __restrict__ props,
                                                const float* __restrict__ gtb,
                                                const int* __restrict__ gtl,
                                                float* __restrict__ out) {
    __shared__ float4 sg[Gn];
    int b = blockIdx.y;
    int p = blockIdx.x * 256 + threadIdx.x;
    if (threadIdx.x < Gn) sg[threadIdx.x] = ((const float4*)(gtb + (size_t)b * Gn * 4))[threadIdx.x];
    __syncthreads();
    if (p >= Nn + Gn) return;
    float4 pb = (p < Nn) ? ((const float4*)(props + (size_t)b * Nn * 4))[p] : sg[p - Nn];
    float areap = (pb.z - pb.x) * (pb.w - pb.y);
    float best = -1.0f; int bi = 0;
    #pragma unroll 4
    for (int g = 0; g < Gn; ++g) {
        float4 gb = sg[g];
        float xx1 = fmaxf(gb.x, pb.x), yy1 = fmaxf(gb.y, pb.y);
        float xx2 = fminf(gb.z, pb.z), yy2 = fminf(gb.w, pb.w);
        float iw = fmaxf(xx2 - xx1, 0.0f), ih = fmaxf(yy2 - yy1, 0.0f);
        float inter = iw * ih;
        float areag = (gb.z - gb.x) * (gb.w - gb.y);
        float iou = inter / (areag + areap - inter);
        if (iou > best) { best = iou; bi = g; }     // strict > : first-max, matches argmax
    }
    float4 gb = sg[bi];
    float pw = pb.z - pb.x, ph = pb.w - pb.y;
    float px = pb.x + 0.5f * pw, py = pb.y + 0.5f * ph;
    float gw = gb.z - gb.x, gh = gb.w - gb.y;
    float gx = gb.x + 0.5f * gw, gy = gb.y + 0.5f * gh;
    float* rr = out + OUT_REG + ((size_t)b * (Nn + Gn) + p) * 4;
    rr[0] = 10.0f * (gx - px) / pw;
    rr[1] = 10.0f * (gy - py) / ph;
    rr[2] = 5.0f * logf(gw / pw);
    rr[3] = 5.0f * logf(gh / ph);
    out[OUT_LBL + (size_t)b * (Nn + Gn) + p] = (best >= 0.5f) ? (float)gtl[b * Gn + bi] : 0.0f;
}

// ---------------- launch ----------------
extern "C" void kernel_launch(void* const* d_in, const int* in_sizes, int n_in,
                              void* d_out, int out_size, void* d_ws, size_t ws_size,
                              hipStream_t stream) {
    const float* props  = (const float*)d_in[0];
    const float* gtb    = (const float*)d_in[1];
    const int*   gtl    = (const int*)d_in[2];
    const float* logits = (const float*)d_in[3];
    const float* regr   = (const float*)d_in[4];
    float* out = (float*)d_out;

    // ws layout — [cnt|cnt2|hist|sel|selkeys] form one contiguous zeroed region
    char* w = (char*)d_ws;
    unsigned int* cnt           = (unsigned int*)(w + 0);                    // 1024 B
    unsigned int* cnt2          = (unsigned int*)(w + 1024);                 // 256 B (16 used)
    unsigned int* hist          = (unsigned int*)(w + 1280);                 // 147456 B
    unsigned long long* sel     = (unsigned long long*)(w + 148736);         // 131072 B
    unsigned long long* selkeys = (unsigned long long*)(w + 279808);         // 65536 B
    const size_t ZERO_BYTES = 345344;
    unsigned long long* keys    = (unsigned long long*)(w + 345344);         // 524288 B
    float* cb                   = (float*)(w + 869632);                      // 131072 B
    float* ob                   = (float*)(w + 1000704);                     // 131072 B
    float* sc                   = (float*)(w + 1131776);                     // 32768 B
    int* lab                    = (int*)(w + 1164544);                       // 32768 B
    unsigned long long* cvw     = (unsigned long long*)(w + 1197312);        // 1024 B
    unsigned long long* M       = (unsigned long long*)(w + 1198336);        // 2097152 B
    (void)ws_size; (void)in_sizes; (void)n_in; (void)out_size;

    hipMemsetAsync(w, 0, ZERO_BYTES, stream);

    fused_cand_k<<<Bn * Nn / 4, 256, 0, stream>>>(logits, regr, props, keys, cnt, hist);
    compact_k<<<Bn * 16, 256, 0, stream>>>(keys, cnt, hist, sel, cnt2);
    rank_k<<<Bn * 64, 256, 0, stream>>>(sel, cnt2, selkeys);
    select_k<<<(Bn * MSEL) / 256, 256, 0, stream>>>(selkeys, props, regr, cb, ob, sc, lab, cvw);
    nmsmat_k<<<Bn * 256, 256, 0, stream>>>(ob, M);
    scan_k<<<Bn, 64, 0, stream>>>(M, cvw, cb, sc, lab, out);
    assign_k<<<dim3((Nn + Gn + 255) / 256, Bn), 256, 0, stream>>>(props, gtb, gtl, out);
}

// Round 6
// 87.774 us; speedup vs baseline: 10.7617x; 1.2834x over previous
//
#include <hip/hip_runtime.h>
#include <cstdint>
#include <cstddef>

// ---- problem constants (match reference) ----
#define Bn   4
#define Nn   4000
#define Gn   64
#define Cn   91
#define FGC  90          // C-1 foreground classes
#define NSEG 64          // counter segments per image (atomic spreading)
#define CAPSEG 256       // key capacity per segment
#define CAPC (NSEG*CAPSEG)  // 16384 per image (V ~ 8K expected)
#define SELCAP 4096      // selected-superset capacity (n2 ~ 2050 expected)
#define MSEL 2048        // PRE_NMS_TOPK
#define DETK 100

__device__ __constant__ float kW = 1333.0f;
__device__ __constant__ float kH = 800.0f;
#define XCLIP 4.135166556742356f   // log(1000/16)
#define OFFMUL 1334.0f             // max(W,H)+1

// score-bit bucketing (uint-monotone for positive floats)
#define NB 9216
#define SBIAS 0x3D400000u

typedef __attribute__((ext_vector_type(2))) unsigned long long u64x2;

// output layout (floats)
#define OUT_DET  0
#define OUT_REG  (Bn*DETK*5)                         // 2000
#define OUT_LBL  (OUT_REG + Bn*(Nn+Gn)*4)            // 67024
#define OUT_DETL (OUT_LBL + Bn*(Nn+Gn))              // 83280

// zeroed region: cnt(1024) + cnt2(256) + hist(147456) = 148736 B
#define ZERO_N16 (148736/16)

// ---------------- decode helper (must be bit-identical between kernels) ----------------
__device__ __forceinline__ void decode_box(float4 p, float4 d,
                                           float& bx1, float& by1, float& bx2, float& by2) {
    float pw = p.z - p.x, ph = p.w - p.y;
    float px = p.x + 0.5f * pw, py = p.y + 0.5f * ph;
    float dx = d.x / 10.0f, dy = d.y / 10.0f;
    float dw = fminf(d.z / 5.0f, XCLIP), dh = fminf(d.w / 5.0f, XCLIP);
    float cx = dx * pw + px, cy = dy * ph + py;
    float w = expf(dw) * pw, h = expf(dh) * ph;
    bx1 = fminf(fmaxf(cx - 0.5f * w, 0.0f), kW);
    by1 = fminf(fmaxf(cy - 0.5f * h, 0.0f), kH);
    bx2 = fminf(fmaxf(cx + 0.5f * w, 0.0f), kW);
    by2 = fminf(fmaxf(cy + 0.5f * h, 0.0f), kH);
}

__device__ __forceinline__ unsigned score_bucket(unsigned sb) {
    unsigned h = (sb - SBIAS) >> 12;
    return h > (NB - 1) ? (NB - 1) : h;
}

// ---------------- kernel 0: zero the counter/histogram region ----------------
__global__ __launch_bounds__(256) void zero_k(uint4* __restrict__ p) {
    int i = blockIdx.x * 256 + threadIdx.x;
    if (i < ZERO_N16) p[i] = make_uint4(0, 0, 0, 0);
}

// ---------------- kernel 1: fused softmax + candidate compaction + histogram ----------------
// 4 rows per wave (4 independent reduction chains = ILP for latency hiding).
// Per-row reduction order is bit-identical to the 1-row version: 64-lane
// butterfly xor 32..1 for max, then for sumexp. One cnt atomic per wave.
__global__ __launch_bounds__(256) void fused_cand_k(const float* __restrict__ logits,
                                                    const float* __restrict__ regr,
                                                    const float* __restrict__ props,
                                                    unsigned long long* __restrict__ keys,
                                                    unsigned int* __restrict__ cnt,
                                                    unsigned int* __restrict__ hist) {
    int wave = threadIdx.x >> 6, lane = threadIdx.x & 63;
    int blk = blockIdx.x;                   // [0,1000), 250 blocks per image
    int rowbase = blk * 16 + wave * 4;      // 4 consecutive rows per wave
    int b = blk / 250;
    int nbase = rowbase - b * Nn;
    bool has1 = (lane + 64) < Cn;           // lane < 27
    const float* z = logits + (size_t)rowbase * Cn;
    float v0[4], v1[4], m[4], e[4];
    #pragma unroll
    for (int r = 0; r < 4; ++r) {
        v0[r] = z[r * Cn + lane];
        v1[r] = has1 ? z[r * Cn + lane + 64] : -INFINITY;
        m[r] = fmaxf(v0[r], v1[r]);
    }
    #pragma unroll
    for (int o = 32; o; o >>= 1) {
        #pragma unroll
        for (int r = 0; r < 4; ++r) m[r] = fmaxf(m[r], __shfl_xor(m[r], o));
    }
    #pragma unroll
    for (int r = 0; r < 4; ++r)
        e[r] = expf(v0[r] - m[r]) + (has1 ? expf(v1[r] - m[r]) : 0.0f);
    #pragma unroll
    for (int o = 32; o; o >>= 1) {
        #pragma unroll
        for (int r = 0; r < 4; ++r) e[r] += __shfl_xor(e[r], o);
    }
    unsigned long long keyA[4], keyB[4];
    bool vA[4], vB[4];
    #pragma unroll
    for (int r = 0; r < 4; ++r) {
        float s0 = expf(v0[r] - m[r]) / e[r];
        float s1 = has1 ? (expf(v1[r] - m[r]) / e[r]) : 0.0f;
        vA[r] = (lane >= 1) && (s0 > 0.05f);
        vB[r] = has1 && (s1 > 0.05f);
        keyA[r] = 0; keyB[r] = 0;
        float4 p = make_float4(0.f, 0.f, 0.f, 0.f);
        if (vA[r] || vB[r]) p = ((const float4*)props)[rowbase + r];
        if (vA[r]) {
            int c = lane;
            float4 d = ((const float4*)regr)[(size_t)(rowbase + r) * Cn + c];
            float bx1, by1, bx2, by2;
            decode_box(p, d, bx1, by1, bx2, by2);
            vA[r] = (bx2 - bx1 >= 0.01f) && (by2 - by1 >= 0.01f);
            unsigned idx = (unsigned)((nbase + r) * FGC + c - 1);
            keyA[r] = ((unsigned long long)__float_as_uint(s0) << 32) | (unsigned long long)(~idx);
            if (vA[r]) atomicAdd(&hist[b * NB + score_bucket(__float_as_uint(s0))], 1u);
        }
        if (vB[r]) {
            int c = lane + 64;
            float4 d = ((const float4*)regr)[(size_t)(rowbase + r) * Cn + c];
            float bx1, by1, bx2, by2;
            decode_box(p, d, bx1, by1, bx2, by2);
            vB[r] = (bx2 - bx1 >= 0.01f) && (by2 - by1 >= 0.01f);
            unsigned idx = (unsigned)((nbase + r) * FGC + c - 1);
            keyB[r] = ((unsigned long long)__float_as_uint(s1) << 32) | (unsigned long long)(~idx);
            if (vB[r]) atomicAdd(&hist[b * NB + score_bucket(__float_as_uint(s1))], 1u);
        }
    }
    // wave-aggregated append: one atomic for all 8 candidate slots
    unsigned long long mk[8];
    #pragma unroll
    for (int r = 0; r < 4; ++r) { mk[2*r] = __ballot(vA[r]); mk[2*r+1] = __ballot(vB[r]); }
    unsigned tot = 0, pre[8];
    #pragma unroll
    for (int q = 0; q < 8; ++q) { pre[q] = tot; tot += (unsigned)__popcll(mk[q]); }
    if (tot) {
        int seg = b * NSEG + (blk & (NSEG - 1));
        unsigned base = 0;
        if (lane == 0) base = atomicAdd(&cnt[seg], tot);
        base = __shfl(base, 0);
        unsigned long long lmask = (lane == 63) ? (~0ull >> 1) : ((1ull << lane) - 1);
        size_t segbase = (size_t)seg * CAPSEG;
        #pragma unroll
        for (int r = 0; r < 4; ++r) {
            if (vA[r]) {
                unsigned pos = base + pre[2*r] + (unsigned)__popcll(mk[2*r] & lmask);
                if (pos < CAPSEG) keys[segbase + pos] = keyA[r];
            }
            if (vB[r]) {
                unsigned pos = base + pre[2*r+1] + (unsigned)__popcll(mk[2*r+1] & lmask);
                if (pos < CAPSEG) keys[segbase + pos] = keyB[r];
            }
        }
    }
}

// ---------------- kernel 2: pivot (per block, redundant) + compact selected superset ----------------
// Selected = keys in buckets >= T, where T is the bucket containing the K2-th
// largest score (K2 = min(V, 2048)). sel[] is a superset, n2 ~ 2050. Append
// order nondeterministic but rank_k canonicalizes it. All sel slots < cnt2
// are written, so sel needs no pre-zeroing.
__global__ __launch_bounds__(256) void compact_k(const unsigned long long* __restrict__ keys,
                                                 const unsigned int* __restrict__ cnt,
                                                 const unsigned int* __restrict__ hist,
                                                 unsigned long long* __restrict__ sel,
                                                 unsigned int* __restrict__ cnt2) {
    int b = blockIdx.x >> 4, blk = blockIdx.x & 15;   // 16 blocks/image, 1024 slots each
    int tid = threadIdx.x, lane = tid & 63, wv = tid >> 6;
    __shared__ unsigned wtot[4], wt2[4], sscnt[NSEG];
    __shared__ unsigned sT, sbase;

    // ---- pivot: each thread owns 36 consecutive buckets ----
    const uint4* h4 = (const uint4*)(hist + b * NB);
    unsigned hc[36]; unsigned s = 0;
    #pragma unroll
    for (int q = 0; q < 9; ++q) {
        uint4 t4 = h4[tid * 9 + q];
        hc[q*4+0] = t4.x; hc[q*4+1] = t4.y; hc[q*4+2] = t4.z; hc[q*4+3] = t4.w;
        s += t4.x + t4.y + t4.z + t4.w;
    }
    unsigned x = s;                                   // wave inclusive suffix scan
    #pragma unroll
    for (int o = 1; o < 64; o <<= 1) { unsigned v = __shfl_down(x, o); if (lane + o < 64) x += v; }
    if (lane == 0) wtot[wv] = x;
    if (tid < NSEG) { unsigned c = cnt[b * NSEG + tid]; sscnt[tid] = c > CAPSEG ? CAPSEG : c; }
    __syncthreads();
    unsigned above = 0, total = 0;
    #pragma unroll
    for (int i2 = 0; i2 < 4; ++i2) { unsigned w2 = wtot[i2]; total += w2; if (i2 > wv) above += w2; }
    unsigned K2 = total < MSEL ? total : MSEL;
    if (K2 == 0) return;                              // cnt2 stays 0 (zero_k)
    unsigned run = (x - s) + above;                   // # keys in buckets above my chunk
    #pragma unroll
    for (int q = 35; q >= 0; --q) {
        unsigned c = hc[q], lo = run;                 // lo = # keys in buckets > (tid*36+q)
        run += c;
        if (lo < K2 && K2 <= run) sT = (unsigned)(tid * 36 + q);
    }
    __syncthreads();
    unsigned T = sT;

    // ---- selection: 4 slots per thread, block-aggregated append ----
    unsigned long long k0 = 0, k1 = 0, k2 = 0, k3 = 0;
    bool v0 = false, v1 = false, v2 = false, v3 = false;
    {
        int g = blk * 1024 + 0 * 256 + tid; unsigned seg = g >> 8, ss = g & 255;
        if (ss < sscnt[seg]) { unsigned long long k = keys[(size_t)b * CAPC + g];
            if (score_bucket((unsigned)(k >> 32)) >= T) { k0 = k; v0 = true; } }
    }
    {
        int g = blk * 1024 + 1 * 256 + tid; unsigned seg = g >> 8, ss = g & 255;
        if (ss < sscnt[seg]) { unsigned long long k = keys[(size_t)b * CAPC + g];
            if (score_bucket((unsigned)(k >> 32)) >= T) { k1 = k; v1 = true; } }
    }
    {
        int g = blk * 1024 + 2 * 256 + tid; unsigned seg = g >> 8, ss = g & 255;
        if (ss < sscnt[seg]) { unsigned long long k = keys[(size_t)b * CAPC + g];
            if (score_bucket((unsigned)(k >> 32)) >= T) { k2 = k; v2 = true; } }
    }
    {
        int g = blk * 1024 + 3 * 256 + tid; unsigned seg = g >> 8, ss = g & 255;
        if (ss < sscnt[seg]) { unsigned long long k = keys[(size_t)b * CAPC + g];
            if (score_bucket((unsigned)(k >> 32)) >= T) { k3 = k; v3 = true; } }
    }
    unsigned c2 = (unsigned)v0 + (unsigned)v1 + (unsigned)v2 + (unsigned)v3;
    unsigned inc = c2;
    #pragma unroll
    for (int o = 1; o < 64; o <<= 1) { unsigned v = __shfl_up(inc, o); if (lane >= o) inc += v; }
    unsigned excl = inc - c2;
    if (lane == 63) wt2[wv] = inc;
    __syncthreads();
    if (tid == 0) {
        unsigned tot = wt2[0] + wt2[1] + wt2[2] + wt2[3];
        sbase = tot ? atomicAdd(&cnt2[b], tot) : 0u;
    }
    __syncthreads();
    unsigned pos = sbase + excl;
    #pragma unroll
    for (int i2 = 0; i2 < 4; ++i2) if (i2 < wv) pos += wt2[i2];
    unsigned long long* selb = sel + (size_t)b * SELCAP;
    unsigned q0 = pos, q1 = q0 + v0, q2 = q1 + v1, q3 = q2 + v2;
    if (v0 && q0 < SELCAP) selb[q0] = k0;
    if (v1 && q1 < SELCAP) selb[q1] = k1;
    if (v2 && q2 < SELCAP) selb[q2] = k2;
    if (v3 && q3 < SELCAP) selb[q3] = k3;
}

// ---------------- kernel 3: rank selected keys -> sorted top-2048 ----------------
// rank(key) = # selected keys greater. Ranks are distinct and cover
// 0..n2-1, so selkeys slots [0, min(n2,MSEL)) are each written exactly once —
// no pre-zeroing needed (select_k masks the tail via cnt2).
__global__ __launch_bounds__(256) void rank_k(const unsigned long long* __restrict__ sel,
                                              const unsigned int* __restrict__ cnt2,
                                              unsigned long long* __restrict__ selkeys) {
    int b = blockIdx.x >> 6, blk = blockIdx.x & 63;   // 64 subject-blocks/image
    unsigned n2 = cnt2[b]; if (n2 > SELCAP) n2 = SELCAP;
    if ((unsigned)(blk * 64) >= n2) return;
    int lane = threadIdx.x & 63, wv = threadIdx.x >> 6;
    int sub = blk * 64 + lane;
    __shared__ __align__(16) unsigned long long skk[SELCAP + 2];
    __shared__ unsigned pc[4][64];
    unsigned n2p = (n2 + 1) & ~1u;
    const unsigned long long* selb = sel + (size_t)b * SELCAP;
    for (unsigned s2 = threadIdx.x; s2 < n2p; s2 += 256)
        skk[s2] = (s2 < n2) ? selb[s2] : 0ull;
    __syncthreads();
    unsigned long long mk = (sub < (int)n2) ? skk[sub] : ~0ull;
    bool act = (sub < (int)n2) && ((mk >> 32) != 0ull);
    unsigned pairs = n2p >> 1;
    unsigned Q = (pairs + 3) >> 2;
    unsigned jb = wv * Q, je = jb + Q; if (je > pairs) je = pairs;
    const u64x2* sk2 = (const u64x2*)skk;
    unsigned cntg = 0;
    for (unsigned j = jb; j < je; ++j) {
        u64x2 kk = sk2[j];
        cntg += (unsigned)(kk.x > mk) + (unsigned)(kk.y > mk);
    }
    pc[wv][lane] = cntg;
    __syncthreads();
    if (wv == 0) {
        unsigned rank = pc[0][lane] + pc[1][lane] + pc[2][lane] + pc[3][lane];
        if (act && rank < MSEL) selkeys[(size_t)b * MSEL + rank] = mk;
    }
}

// ---------------- kernel 4: materialize selected candidates ----------------
__global__ __launch_bounds__(256) void select_k(const unsigned long long* __restrict__ selkeys,
                                                const unsigned int* __restrict__ cnt2,
                                                const float* __restrict__ props,
                                                const float* __restrict__ regr,
                                                float* __restrict__ cb, float* __restrict__ ob,
                                                float* __restrict__ sc, int* __restrict__ lab,
                                                unsigned long long* __restrict__ cvw) {
    int t = blockIdx.x * 256 + threadIdx.x;        // B*2048
    if (t >= Bn * MSEL) return;
    int b = t >> 11;
    unsigned n2 = cnt2[b]; if (n2 > SELCAP) n2 = SELCAP;
    unsigned validN = n2 < MSEL ? n2 : MSEL;       // # selkeys slots actually written
    unsigned slotrank = (unsigned)(t & (MSEL - 1));
    unsigned long long key = (slotrank < validN) ? selkeys[t] : 0ull;
    float bx1 = 0, by1 = 0, bx2 = 0, by2 = 0, score = 0;
    int c = 0; unsigned valid = 0;
    if ((key >> 32) != 0ull) {
        valid = 1;
        unsigned idx = ~(unsigned)key;
        int n = idx / FGC, cm1 = idx - n * FGC;
        c = cm1 + 1;
        score = __uint_as_float((unsigned)(key >> 32));
        int row = b * Nn + n;
        float4 p = ((const float4*)props)[row];
        float4 d = ((const float4*)regr)[(size_t)row * Cn + c];
        decode_box(p, d, bx1, by1, bx2, by2);
    }
    float off = (float)c * OFFMUL;
    cb[t * 4 + 0] = bx1; cb[t * 4 + 1] = by1; cb[t * 4 + 2] = bx2; cb[t * 4 + 3] = by2;
    ob[t * 4 + 0] = bx1 + off; ob[t * 4 + 1] = by1 + off;
    ob[t * 4 + 2] = bx2 + off; ob[t * 4 + 3] = by2 + off;
    sc[t] = score; lab[t] = c;
    unsigned long long bw = __ballot(valid != 0u); // pack keep-init words here
    if ((t & 63) == 0) cvw[t >> 6] = bw;
}

// ---------------- kernel 5: suppression bitmask matrix M[b][i][w] ----------------
__global__ __launch_bounds__(256) void nmsmat_k(const float* __restrict__ ob,
                                                unsigned long long* __restrict__ M) {
    int blk = blockIdx.x;                 // Bn * 8 * 32
    int b = blk >> 8, rc = (blk >> 5) & 7, w = blk & 31;
    int i = rc * 256 + threadIdx.x;
    size_t mi = ((size_t)b * MSEL + i) * 32 + w;
    if (w * 64 + 63 <= rc * 256) {        // all j <= min i: bits provably zero
        M[mi] = 0ull;                     // must write (ws is poisoned)
        return;
    }
    __shared__ float4 sj[64];
    const float4* obf4 = (const float4*)(ob + (size_t)b * MSEL * 4);
    if (threadIdx.x < 64) sj[threadIdx.x] = obf4[w * 64 + threadIdx.x];
    __syncthreads();
    float4 bi = obf4[i];
    float areai = (bi.z - bi.x) * (bi.w - bi.y);
    unsigned long long bits = 0ull;
    #pragma unroll 16
    for (int tt = 0; tt < 64; ++tt) {
        int j = w * 64 + tt;
        float4 bj = sj[tt];               // wave-uniform LDS read -> broadcast
        float xx1 = fmaxf(bi.x, bj.x), yy1 = fmaxf(bi.y, bj.y);
        float xx2 = fminf(bi.z, bj.z), yy2 = fminf(bi.w, bj.w);
        float iw = fmaxf(xx2 - xx1, 0.0f), ih = fmaxf(yy2 - yy1, 0.0f);
        float inter = iw * ih;
        float areaj = (bj.z - bj.x) * (bj.w - bj.y);
        float iou = inter / (areai + areaj - inter);   // NaN>0.5 is false: matches JAX
        if ((iou > 0.5f) && (j > i)) bits |= (1ull << tt);
    }
    M[mi] = bits;
}

// ---------------- kernel 6: sequential greedy scan (one wave per image) + det output ----------------
__global__ __launch_bounds__(64) void scan_k(const unsigned long long* __restrict__ M,
                                             const unsigned long long* __restrict__ cvw,
                                             const float* __restrict__ cb,
                                             const float* __restrict__ sc,
                                             const int* __restrict__ lab,
                                             float* __restrict__ out) {
    int b = blockIdx.x, lane = threadIdx.x;
    const bool ld = lane < 32;
    unsigned long long keep = ld ? cvw[b * 32 + lane] : 0ull;
    unsigned kLo = (unsigned)keep, kHi = (unsigned)(keep >> 32);
    __shared__ int keptIdx[DETK];
    const unsigned long long* Mb = M + (size_t)b * MSEL * 32;
    int kcount = 0;                                 // wave-uniform (tests come from readlane)
    unsigned long long Abuf[16], Bbuf[16];
    #pragma unroll
    for (int k = 0; k < 16; ++k) Abuf[k] = ld ? Mb[(size_t)k * 32 + lane] : 0ull;
    for (int g = 0; g < 128; g += 2) {
        #pragma unroll
        for (int k = 0; k < 16; ++k)
            Bbuf[k] = ld ? Mb[(size_t)((g + 1) * 16 + k) * 32 + lane] : 0ull;
        {
            int base = g * 16;
            int rl = base >> 6, sh = base & 31;     // uniform within group
            unsigned half = (base >> 5) & 1;
            #pragma unroll
            for (int k = 0; k < 16; ++k) {
                unsigned kw = half ? kHi : kLo;
                unsigned bitv = (__builtin_amdgcn_readlane(kw, rl) >> (sh + k)) & 1u;
                if (bitv) {
                    unsigned long long m = Abuf[k];
                    kLo &= ~(unsigned)m; kHi &= ~(unsigned)(m >> 32);
                    if (kcount < DETK && lane == 0) keptIdx[kcount] = base + k;
                    ++kcount;
                }
            }
        }
        if (kcount >= DETK) break;
        if (g + 2 < 128) {
            #pragma unroll
            for (int k = 0; k < 16; ++k)
                Abuf[k] = ld ? Mb[(size_t)((g + 2) * 16 + k) * 32 + lane] : 0ull;
        }
        {
            int base = (g + 1) * 16;
            int rl = base >> 6, sh = base & 31;
            unsigned half = (base >> 5) & 1;
            #pragma unroll
            for (int k = 0; k < 16; ++k) {
                unsigned kw = half ? kHi : kLo;
                unsigned bitv = (__builtin_amdgcn_readlane(kw, rl) >> (sh + k)) & 1u;
                if (bitv) {
                    unsigned long long m = Bbuf[k];
                    kLo &= ~(unsigned)m; kHi &= ~(unsigned)(m >> 32);
                    if (kcount < DETK && lane == 0) keptIdx[kcount] = base + k;
                    ++kcount;
                }
            }
        }
        if (kcount >= DETK) break;
    }
    __syncthreads();                                // lgkmcnt drain for keptIdx
    int kept100 = kcount < DETK ? kcount : DETK;
    for (int r = lane; r < kept100; r += 64) {
        int i = keptIdx[r];
        int slot = b * MSEL + i;
        float* dr = out + OUT_DET + ((size_t)b * DETK + r) * 5;
        dr[0] = cb[slot * 4 + 0]; dr[1] = cb[slot * 4 + 1];
        dr[2] = cb[slot * 4 + 2]; dr[3] = cb[slot * 4 + 3];
        dr[4] = sc[slot];
        out[OUT_DETL + b * DETK + r] = (float)lab[slot];
    }
    for (int r = kept100 + lane; r < DETK; r += 64) {
        float* dr = out + OUT_DET + ((size_t)b * DETK + r) * 5;
        dr[0] = dr[1] = dr[2] = dr[3] = dr[4] = 0.0f;
        out[OUT_DETL + b * DETK + r] = 0.0f;
    }
}

// ---------------- kernel 7: proposal->gt matching, reg_targets + lbl ----------------
__global__ __launch_bounds__(256) void assign_k(const float* __restrict__ props,
                                                const float* __restrict__ gtb,
                                                const int* __restrict__ gtl,
                                                float* __restrict__ out) {
    __shared__ float4 sg[Gn];
    int b = blockIdx.y;
    int p = blockIdx.x * 256 + threadIdx.x;
    if (threadIdx.x < Gn) sg[threadIdx.x] = ((const float4*)(gtb + (size_t)b * Gn * 4))[threadIdx.x];
    __syncthreads();
    if (p >= Nn + Gn) return;
    float4 pb = (p < Nn) ? ((const float4*)(props + (size_t)b * Nn * 4))[p] : sg[p - Nn];
    float areap = (pb.z - pb.x) * (pb.w - pb.y);
    float best = -1.0f; int bi = 0;
    #pragma unroll 4
    for (int g = 0; g < Gn; ++g) {
        float4 gb = sg[g];
        float xx1 = fmaxf(gb.x, pb.x), yy1 = fmaxf(gb.y, pb.y);
        float xx2 = fminf(gb.z, pb.z), yy2 = fminf(gb.w, pb.w);
        float iw = fmaxf(xx2 - xx1, 0.0f), ih = fmaxf(yy2 - yy1, 0.0f);
        float inter = iw * ih;
        float areag = (gb.z - gb.x) * (gb.w - gb.y);
        float iou = inter / (areag + areap - inter);
        if (iou > best) { best = iou; bi = g; }     // strict > : first-max, matches argmax
    }
    float4 gb = sg[bi];
    float pw = pb.z - pb.x, ph = pb.w - pb.y;
    float px = pb.x + 0.5f * pw, py = pb.y + 0.5f * ph;
    float gw = gb.z - gb.x, gh = gb.w - gb.y;
    float gx = gb.x + 0.5f * gw, gy = gb.y + 0.5f * gh;
    float* rr = out + OUT_REG + ((size_t)b * (Nn + Gn) + p) * 4;
    rr[0] = 10.0f * (gx - px) / pw;
    rr[1] = 10.0f * (gy - py) / ph;
    rr[2] = 5.0f * logf(gw / pw);
    rr[3] = 5.0f * logf(gh / ph);
    out[OUT_LBL + (size_t)b * (Nn + Gn) + p] = (best >= 0.5f) ? (float)gtl[b * Gn + bi] : 0.0f;
}

// ---------------- launch ----------------
extern "C" void kernel_launch(void* const* d_in, const int* in_sizes, int n_in,
                              void* d_out, int out_size, void* d_ws, size_t ws_size,
                              hipStream_t stream) {
    const float* props  = (const float*)d_in[0];
    const float* gtb    = (const float*)d_in[1];
    const int*   gtl    = (const int*)d_in[2];
    const float* logits = (const float*)d_in[3];
    const float* regr   = (const float*)d_in[4];
    float* out = (float*)d_out;

    // ws layout — [cnt|cnt2|hist] is the only region needing zeroing
    char* w = (char*)d_ws;
    unsigned int* cnt           = (unsigned int*)(w + 0);                    // 1024 B
    unsigned int* cnt2          = (unsigned int*)(w + 1024);                 // 256 B (16 used)
    unsigned int* hist          = (unsigned int*)(w + 1280);                 // 147456 B
    unsigned long long* sel     = (unsigned long long*)(w + 148736);         // 131072 B (no zero needed)
    unsigned long long* selkeys = (unsigned long long*)(w + 279808);         // 65536 B (no zero needed)
    unsigned long long* keys    = (unsigned long long*)(w + 345344);         // 524288 B
    float* cb                   = (float*)(w + 869632);                      // 131072 B
    float* ob                   = (float*)(w + 1000704);                     // 131072 B
    float* sc                   = (float*)(w + 1131776);                     // 32768 B
    int* lab                    = (int*)(w + 1164544);                       // 32768 B
    unsigned long long* cvw     = (unsigned long long*)(w + 1197312);        // 1024 B
    unsigned long long* M       = (unsigned long long*)(w + 1198336);        // 2097152 B
    (void)ws_size; (void)in_sizes; (void)n_in; (void)out_size;

    zero_k<<<(ZERO_N16 + 255) / 256, 256, 0, stream>>>((uint4*)w);
    fused_cand_k<<<Bn * Nn / 16, 256, 0, stream>>>(logits, regr, props, keys, cnt, hist);
    compact_k<<<Bn * 16, 256, 0, stream>>>(keys, cnt, hist, sel, cnt2);
    rank_k<<<Bn * 64, 256, 0, stream>>>(sel, cnt2, selkeys);
    select_k<<<(Bn * MSEL) / 256, 256, 0, stream>>>(selkeys, cnt2, props, regr, cb, ob, sc, lab, cvw);
    nmsmat_k<<<Bn * 256, 256, 0, stream>>>(ob, M);
    scan_k<<<Bn, 64, 0, stream>>>(M, cvw, cb, sc, lab, out);
    assign_k<<<dim3((Nn + Gn + 255) / 256, Bn), 256, 0, stream>>>(props, gtb, gtl, out);
}